// Round 12
// baseline (2409.697 us; speedup 1.0000x reference)
//
#include <hip/hip_runtime.h>

#define SB 512  // scan tile size

__device__ inline unsigned short f2bf(float f) {
    unsigned u = __float_as_uint(f);
    unsigned r = (u + 0x7fffu + ((u >> 16) & 1u)) >> 16;   // round-nearest-even
    return (unsigned short)r;
}

// ---------------- CSR build (rank captured in count pass; fill is atomic-free) ----------------
__global__ void count_rank_kernel(const int* __restrict__ from_idx, const int* __restrict__ to_idx,
                                  int* __restrict__ cnt_to, int* __restrict__ cnt_from,
                                  int* __restrict__ rank_to, int* __restrict__ rank_from, int E) {
    int e = blockIdx.x * blockDim.x + threadIdx.x;
    if (e >= E) return;
    int f = from_idx[e], t = to_idx[e];
    rank_to[e] = atomicAdd(&cnt_to[t], 1);
    rank_from[e] = atomicAdd(&cnt_from[f], 1);
}

// ---- hierarchical scan: A) block sums, B) scan of block sums, C) block scan + base ----
__global__ void __launch_bounds__(SB) scanA_kernel(const int* __restrict__ cnt_to,
                                                   const int* __restrict__ cnt_from,
                                                   int* __restrict__ bsum, int nblk, int N) {
    const int* cnt = blockIdx.y ? cnt_from : cnt_to;
    __shared__ int s[SB];
    int tid = threadIdx.x;
    int i = blockIdx.x * SB + tid;
    s[tid] = (i < N) ? cnt[i] : 0;
    __syncthreads();
    for (int d = SB / 2; d > 0; d >>= 1) {
        if (tid < d) s[tid] += s[tid + d];
        __syncthreads();
    }
    if (tid == 0) bsum[blockIdx.y * nblk + blockIdx.x] = s[0];
}

__global__ void scanB_kernel(int* __restrict__ bsum, int* __restrict__ bbase,
                             int* __restrict__ off_to, int* __restrict__ off_from,
                             int nblk, int N) {
    int tid = threadIdx.x;
    if (tid < 2) {
        const int* bs = bsum + tid * nblk;
        int* bb = bbase + tid * nblk;
        int run = 0;
        for (int i = 0; i < nblk; ++i) { bb[i] = run; run += bs[i]; }
        if (tid == 0) off_to[N] = run; else off_from[N] = run;
    }
}

__global__ void __launch_bounds__(SB) scanC_kernel(const int* __restrict__ cnt_to,
                                                   const int* __restrict__ cnt_from,
                                                   const int* __restrict__ bbase,
                                                   int* __restrict__ off_to, int* __restrict__ off_from,
                                                   int nblk, int N) {
    const int* cnt = blockIdx.y ? cnt_from : cnt_to;
    int* off = blockIdx.y ? off_from : off_to;
    __shared__ int s[SB];
    int tid = threadIdx.x;
    int i = blockIdx.x * SB + tid;
    int v = (i < N) ? cnt[i] : 0;
    s[tid] = v;
    __syncthreads();
    for (int d = 1; d < SB; d <<= 1) {
        int t = s[tid];
        int add = (tid >= d) ? s[tid - d] : 0;
        __syncthreads();
        s[tid] = t + add;
        __syncthreads();
    }
    if (i < N) off[i] = s[tid] - v + bbase[blockIdx.y * nblk + blockIdx.x];
}

__global__ void fill_kernel(const int* __restrict__ from_idx, const int* __restrict__ to_idx,
                            const int* __restrict__ off_to, const int* __restrict__ off_from,
                            const int* __restrict__ rank_to, const int* __restrict__ rank_from,
                            int* __restrict__ list_to, int* __restrict__ list_from, int E) {
    int e = blockIdx.x * blockDim.x + threadIdx.x;
    if (e >= E) return;
    int f = from_idx[e], t = to_idx[e];
    list_to[off_to[t] + rank_to[e]] = f;
    list_from[off_from[f] + rank_from[e]] = t;
}

// ---------------- Whh transpose ----------------
__global__ void transpose_whh(const float* __restrict__ Whh, float* __restrict__ WhhT) {
    int idx = blockIdx.x * 256 + threadIdx.x;
    if (idx >= 3 * 32 * 96) return;
    int l = idx / 3072, r = idx % 3072;
    int j = r / 96, k = r % 96;
    WhhT[idx] = Whh[l * 3072 + k * 32 + j];
}

// ---------------- compose: M1 = W2 @ Wih^T, M2 = rW2 @ Wih^T, v = b @ Wih^T ----------------
__global__ void compose_kernel(const float* __restrict__ W2, const float* __restrict__ rW2,
                               const float* __restrict__ Wih,
                               const float* __restrict__ b2, const float* __restrict__ rb2,
                               float* __restrict__ M1, float* __restrict__ M2,
                               float* __restrict__ v12) {
    int l = blockIdx.x / 97, j = blockIdx.x % 97;
    int k = threadIdx.x;  // 96
    const float* wih = Wih + l * 9216 + k * 96;
    if (j < 96) {
        const float* w2  = W2 + l * 9216 + j * 96;
        const float* rw2 = rW2 + l * 9216 + j * 96;
        float a1 = 0.f, a2 = 0.f;
        for (int m = 0; m < 96; ++m) {
            float wv = wih[m];
            a1 = fmaf(w2[m], wv, a1);
            a2 = fmaf(rw2[m], wv, a2);
        }
        M1[l * 9216 + j * 96 + k] = a1;
        M2[l * 9216 + j * 96 + k] = a2;
    } else {
        const float* bb = b2 + l * 96;
        const float* rbb = rb2 + l * 96;
        float a1 = 0.f, a2 = 0.f;
        for (int m = 0; m < 96; ++m) {
            float wv = wih[m];
            a1 = fmaf(bb[m], wv, a1);
            a2 = fmaf(rbb[m], wv, a2);
        }
        v12[l * 192 + k] = a1;
        v12[l * 192 + 96 + k] = a2;
    }
}

// ---------------- encoder: h = IN@W + b (r10 layout: stride-33, b32 reads, 0 conflicts) ---------
__global__ void __launch_bounds__(256) enc_gemm(const float* __restrict__ IN,
                                                const float* __restrict__ W, const float* __restrict__ bias,
                                                float* __restrict__ OUT, int N) {
    __shared__ float tile[64][33];
    int n0 = blockIdx.x * 64, tid = threadIdx.x;
    for (int idx = tid; idx < 64 * 32; idx += 256) {
        int r = idx >> 5, c = idx & 31;
        int n = n0 + r;
        tile[r][c] = (n < N) ? IN[(long)n * 32 + c] : 0.f;
    }
    __syncthreads();
    int lane = tid & 63;
    int w = __builtin_amdgcn_readfirstlane(tid >> 6);
    float acc[8] = {0};
    const float* Wp = W + w * 8;
#pragma unroll 4
    for (int j = 0; j < 32; ++j) {
        float a = tile[lane][j];
#pragma unroll
        for (int c = 0; c < 8; ++c) acc[c] = fmaf(a, Wp[j * 32 + c], acc[c]);
    }
    int n = n0 + lane;
    if (n >= N) return;
    float* outp = OUT + (long)n * 32 + w * 8;
#pragma unroll
    for (int c = 0; c < 8; ++c) outp[c] = acc[c] + bias[w * 8 + c];
}

// ---------------- projections (r10 layout: stride-33, b32 reads) ----------------
__global__ void __launch_bounds__(256) proj_kernel(
    const float* __restrict__ h,
    const float* __restrict__ W1f, const float* __restrict__ b1f,
    const float* __restrict__ W1r, const float* __restrict__ b1r,
    unsigned* __restrict__ PaFu, float* __restrict__ PbF,
    unsigned* __restrict__ PaRu, float* __restrict__ PbR, int N)
{
    const float* W1 = blockIdx.y ? W1r : W1f;
    const float* b1 = blockIdx.y ? b1r : b1f;
    unsigned* PaU = blockIdx.y ? PaRu : PaFu;
    float* Pb = blockIdx.y ? PbR : PbF;
    __shared__ float tile[64][33];
    int n0 = blockIdx.x * 64, tid = threadIdx.x;
    for (int idx = tid; idx < 64 * 32; idx += 256) {
        int r = idx >> 5, c = idx & 31;
        int n = n0 + r;
        tile[r][c] = (n < N) ? h[(long)n * 32 + c] : 0.f;
    }
    __syncthreads();
    int lane = tid & 63;
    int w = __builtin_amdgcn_readfirstlane(tid >> 6);
    int c0 = w * 48;
    const float* Wp = (c0 < 96) ? (W1 + c0) : (W1 + 32 * 96 + (c0 - 96));
    float acc[48];
#pragma unroll
    for (int c = 0; c < 48; ++c) acc[c] = 0.f;
#pragma unroll 2
    for (int j = 0; j < 32; ++j) {
        float a = tile[lane][j];
#pragma unroll
        for (int c = 0; c < 48; ++c) acc[c] = fmaf(a, Wp[j * 96 + c], acc[c]);
    }
    int n = n0 + lane;
    if (n >= N) return;
    if (c0 < 96) {
        unsigned* pap = PaU + (long)n * 48 + (c0 >> 1);
#pragma unroll
        for (int c = 0; c < 24; ++c)
            pap[c] = (unsigned)f2bf(acc[2 * c]) | ((unsigned)f2bf(acc[2 * c + 1]) << 16);
    } else {
        float* outp = Pb + (long)n * 96 + (c0 - 96);
#pragma unroll
        for (int c = 0; c < 48; ++c) outp[c] = acc[c] + b1[c0 - 96 + c];
    }
}

// ---------------- edge aggregation: 8 gathers in flight ----------------
__global__ void __launch_bounds__(256) agg_bf16(
    const int* __restrict__ offF, const int* __restrict__ listF,
    const int* __restrict__ offR, const int* __restrict__ listR,
    const unsigned* __restrict__ PaF, const unsigned* __restrict__ PaR,
    float* PbF, float* PbR, int N)
{
    const int* off; const int* list; const unsigned* Pa; float* Pb;
    if (blockIdx.y == 0) { off = offF; list = listF; Pa = PaF; Pb = PbF; }
    else                 { off = offR; list = listR; Pa = PaR; Pb = PbR; }
    int n = __builtin_amdgcn_readfirstlane((blockIdx.x * 256 + threadIdx.x) >> 6);
    int lane = threadIdx.x & 63;
    if (n >= N) return;
    int li = (lane < 48) ? lane : 47;
    bool act = lane < 48;
    long pbase = (long)n * 96 + 2 * li;
    float sx = 0.f, sy = 0.f;
    if (act) { float2 s = *(const float2*)(Pb + pbase); sx = s.x; sy = s.y; }
    float a0 = 0.f, a1 = 0.f;
    int beg = off[n], end = off[n + 1];
    int i = beg;
    for (; i + 8 <= end; i += 8) {              // 8 gathers in flight
        unsigned u[8];
#pragma unroll
        for (int q = 0; q < 8; ++q) u[q] = Pa[(long)list[i + q] * 48 + li];
#pragma unroll
        for (int q = 0; q < 8; ++q) {
            a0 += fmaxf(__uint_as_float(u[q] << 16) + sx, 0.f);
            a1 += fmaxf(__uint_as_float(u[q] & 0xffff0000u) + sy, 0.f);
        }
    }
    for (; i < end; ++i) {
        unsigned u = Pa[(long)list[i] * 48 + li];
        a0 += fmaxf(__uint_as_float(u << 16) + sx, 0.f);
        a1 += fmaxf(__uint_as_float(u & 0xffff0000u) + sy, 0.f);
    }
    if (act) { *(float2*)(Pb + pbase) = make_float2(a0, a1); }
}

// ---------------- fused gates+GRU v3: NO LDS. Per-lane row loads direct to registers ----------
// A-loads go on vmcnt (decoupled from s_load weights on lgkmcnt); no barriers; occupancy grid-capped.
__global__ void __launch_bounds__(512) gru2_kernel(
    const float* __restrict__ AF, const float* __restrict__ AR,
    const float* __restrict__ M1, const float* __restrict__ M2,
    const float* __restrict__ v12,
    const int* __restrict__ offF, const int* __restrict__ offR,
    const float* __restrict__ h, const float* __restrict__ WhhT,
    const float* __restrict__ bih, const float* __restrict__ bhh,
    float* __restrict__ hout, int N)
{
    int n0 = blockIdx.x * 64, tid = threadIdx.x;
    int lane = tid & 63;
    int w = __builtin_amdgcn_readfirstlane(tid >> 6);   // 0..7
    int w4 = w * 4;
    int n = n0 + lane;
    int nb = (n < N) ? n : (N - 1);
    const float* afr = AF + (long)nb * 96;
    const float* arr = AR + (long)nb * 96;

    float acc[12];
#pragma unroll
    for (int c = 0; c < 12; ++c) acc[c] = 0.f;

    const float* M1w = M1 + w4;
#pragma unroll
    for (int half = 0; half < 2; ++half) {
        float a[48];
#pragma unroll
        for (int q = 0; q < 12; ++q) {          // 12 global dwordx4 in flight (vmcnt)
            float4 v = *(const float4*)(afr + half * 48 + q * 4);
            a[q * 4] = v.x; a[q * 4 + 1] = v.y; a[q * 4 + 2] = v.z; a[q * 4 + 3] = v.w;
        }
#pragma unroll
        for (int u = 0; u < 48; ++u) {
            const float* Wr = M1w + (half * 48 + u) * 96;   // uniform -> s_load imm-offset
#pragma unroll
            for (int g = 0; g < 3; ++g)
#pragma unroll
                for (int i = 0; i < 4; ++i)
                    acc[g * 4 + i] = fmaf(a[u], Wr[g * 32 + i], acc[g * 4 + i]);
        }
    }
    const float* M2w = M2 + w4;
#pragma unroll
    for (int half = 0; half < 2; ++half) {
        float a[48];
#pragma unroll
        for (int q = 0; q < 12; ++q) {
            float4 v = *(const float4*)(arr + half * 48 + q * 4);
            a[q * 4] = v.x; a[q * 4 + 1] = v.y; a[q * 4 + 2] = v.z; a[q * 4 + 3] = v.w;
        }
#pragma unroll
        for (int u = 0; u < 48; ++u) {
            const float* Wr = M2w + (half * 48 + u) * 96;
#pragma unroll
            for (int g = 0; g < 3; ++g)
#pragma unroll
                for (int i = 0; i < 4; ++i)
                    acc[g * 4 + i] = fmaf(a[u], Wr[g * 32 + i], acc[g * 4 + i]);
        }
    }
    // degree/bias corrections
    float dF = (float)(offF[nb + 1] - offF[nb]);
    float dR = (float)(offR[nb + 1] - offR[nb]);
    const float* v1 = v12;
    const float* v2 = v12 + 96;
#pragma unroll
    for (int g = 0; g < 3; ++g)
#pragma unroll
        for (int i = 0; i < 4; ++i) {
            int col = g * 32 + w4 + i;
            acc[g * 4 + i] += dF * v1[col] + dR * v2[col] + bih[col];
        }
    // GH = h @ Whh^T  (h row in registers, static indices)
    float hr[32];
#pragma unroll
    for (int q = 0; q < 8; ++q) {
        float4 v = *(const float4*)(h + (long)nb * 32 + q * 4);
        hr[q * 4] = v.x; hr[q * 4 + 1] = v.y; hr[q * 4 + 2] = v.z; hr[q * 4 + 3] = v.w;
    }
    float acc2[12];
#pragma unroll
    for (int c = 0; c < 12; ++c) acc2[c] = 0.f;
#pragma unroll
    for (int j = 0; j < 32; ++j) {
        const float* Wr = WhhT + j * 96 + w4;
#pragma unroll
        for (int g = 0; g < 3; ++g)
#pragma unroll
            for (int i = 0; i < 4; ++i)
                acc2[g * 4 + i] = fmaf(hr[j], Wr[g * 32 + i], acc2[g * 4 + i]);
    }
    if (n < N) {
        float4 hb = *(const float4*)(h + (long)n * 32 + w4);   // z*h term (static components)
        float hv[4] = {hb.x, hb.y, hb.z, hb.w};
        float ov[4];
#pragma unroll
        for (int i = 0; i < 4; ++i) {
            int c0 = w4 + i, c1 = 32 + w4 + i, c2 = 64 + w4 + i;
            float r = 1.f / (1.f + __expf(-(acc[i] + acc2[i] + bhh[c0])));
            float z = 1.f / (1.f + __expf(-(acc[4 + i] + acc2[4 + i] + bhh[c1])));
            float nn = tanhf(acc[8 + i] + r * (acc2[8 + i] + bhh[c2]));
            ov[i] = (1.f - z) * nn + z * hv[i];
        }
        float4 o; o.x = ov[0]; o.y = ov[1]; o.z = ov[2]; o.w = ov[3];
        *(float4*)(hout + (long)n * 32 + w4) = o;
    }
}

// ---------------- graph aggregator: weights hoisted to registers, chunk=32 ----------------
__global__ void __launch_bounds__(128) graph_agg(const float* __restrict__ h, const float* __restrict__ W1,
                          const float* __restrict__ b1, const int* __restrict__ gidx,
                          float* __restrict__ gs, int N, int chunk) {
    int k = threadIdx.x;  // 128
    int n_start = blockIdx.x * chunk;
    if (n_start >= N) return;
    int n_end = min(n_start + chunk, N);
    float w1[32], w2[32];
#pragma unroll
    for (int j = 0; j < 32; ++j) {
        w1[j] = W1[j * 256 + k];
        w2[j] = W1[j * 256 + 128 + k];
    }
    float bb1 = b1[k], bb2 = b1[128 + k];
    float acc = 0.f;
    int cur = gidx[n_start];
    for (int n = n_start; n < n_end; ++n) {
        int g = gidx[n];
        if (g != cur) { atomicAdd(&gs[cur * 128 + k], acc); acc = 0.f; cur = g; }
        float g1 = bb1, g2 = bb2;
#pragma unroll
        for (int j = 0; j < 32; ++j) {
            float hv = h[(long)n * 32 + j];
            g1 = fmaf(hv, w1[j], g1);
            g2 = fmaf(hv, w2[j], g2);
        }
        acc += (1.f / (1.f + __expf(-g1))) * g2;
    }
    atomicAdd(&gs[cur * 128 + k], acc);
}

__global__ void final_gemm(const float* __restrict__ gs, const float* __restrict__ W,
                           const float* __restrict__ b, float* __restrict__ out) {
    int g = blockIdx.x, k = threadIdx.x;
    float a = b[k];
#pragma unroll 8
    for (int j = 0; j < 128; ++j) a = fmaf(gs[g * 128 + j], W[j * 128 + k], a);
    out[g * 128 + k] = a;
}

extern "C" void kernel_launch(void* const* d_in, const int* in_sizes, int n_in,
                              void* d_out, int out_size, void* d_ws, size_t ws_size,
                              hipStream_t stream) {
    const float* node_features = (const float*)d_in[0];
    const float* enc_W  = (const float*)d_in[1];
    const float* enc_b  = (const float*)d_in[2];
    const float* msg_W1 = (const float*)d_in[3];
    const float* msg_b1 = (const float*)d_in[4];
    const float* msg_W2 = (const float*)d_in[5];
    const float* msg_b2 = (const float*)d_in[6];
    const float* rmsg_W1 = (const float*)d_in[7];
    const float* rmsg_b1 = (const float*)d_in[8];
    const float* rmsg_W2 = (const float*)d_in[9];
    const float* rmsg_b2 = (const float*)d_in[10];
    const float* gru_Wih = (const float*)d_in[11];
    const float* gru_Whh = (const float*)d_in[12];
    const float* gru_bih = (const float*)d_in[13];
    const float* gru_bhh = (const float*)d_in[14];
    const float* agg_W1 = (const float*)d_in[15];
    const float* agg_b1 = (const float*)d_in[16];
    const float* agg_W2 = (const float*)d_in[17];
    const float* agg_b2 = (const float*)d_in[18];
    const int* from_idx = (const int*)d_in[19];
    const int* to_idx   = (const int*)d_in[20];
    const int* graph_idx = (const int*)d_in[21];

    const int N = in_sizes[0] / 32;
    const int E = in_sizes[19];
    const int NG = out_size / 128;
    float* out = (float*)d_out;

    char* ws = (char*)d_ws;
    auto alloc = [&](size_t b) { void* p = (void*)ws; ws += (b + 255) & ~(size_t)255; return p; };
    int* cnt_to   = (int*)alloc((size_t)N * 4);
    int* cnt_from = (int*)alloc((size_t)N * 4);
    int* off_to   = (int*)alloc((size_t)(N + 1) * 4);
    int* off_from = (int*)alloc((size_t)(N + 1) * 4);
    int* list_to  = (int*)alloc((size_t)E * 4);
    int* list_from= (int*)alloc((size_t)E * 4);
    float* h0  = (float*)alloc((size_t)N * 32 * 4);
    float* h1  = (float*)alloc((size_t)N * 32 * 4);
    unsigned* PaF = (unsigned*)alloc((size_t)N * 48 * 4);
    unsigned* PaR = (unsigned*)alloc((size_t)N * 48 * 4);
    float* PbF = (float*)alloc((size_t)N * 96 * 4);
    float* PbR = (float*)alloc((size_t)N * 96 * 4);
    float* WhhT = (float*)alloc((size_t)3 * 32 * 96 * 4);
    float* M1   = (float*)alloc((size_t)3 * 96 * 96 * 4);
    float* M2   = (float*)alloc((size_t)3 * 96 * 96 * 4);
    float* v12  = (float*)alloc((size_t)3 * 192 * 4);
    float* gs   = (float*)alloc((size_t)NG * 128 * 4);
    const int nblk = (N + SB - 1) / SB;
    int* bsum  = (int*)alloc((size_t)2 * nblk * 4);
    int* bbase = (int*)alloc((size_t)2 * nblk * 4);
    // rank arrays alias Pb buffers (dead before proj writes them)
    int* rank_to   = (int*)PbF;
    int* rank_from = (int*)PbR;

    hipMemsetAsync(cnt_to, 0, (size_t)N * 4, stream);
    hipMemsetAsync(cnt_from, 0, (size_t)N * 4, stream);
    hipMemsetAsync(gs, 0, (size_t)NG * 128 * 4, stream);

    int gE = (E + 255) / 256;
    count_rank_kernel<<<gE, 256, 0, stream>>>(from_idx, to_idx, cnt_to, cnt_from, rank_to, rank_from, E);
    dim3 gScan(nblk, 2);
    scanA_kernel<<<gScan, SB, 0, stream>>>(cnt_to, cnt_from, bsum, nblk, N);
    scanB_kernel<<<1, 64, 0, stream>>>(bsum, bbase, off_to, off_from, nblk, N);
    scanC_kernel<<<gScan, SB, 0, stream>>>(cnt_to, cnt_from, bbase, off_to, off_from, nblk, N);
    fill_kernel<<<gE, 256, 0, stream>>>(from_idx, to_idx, off_to, off_from, rank_to, rank_from,
                                        list_to, list_from, E);

    transpose_whh<<<(3 * 32 * 96 + 255) / 256, 256, 0, stream>>>(gru_Whh, WhhT);
    compose_kernel<<<3 * 97, 96, 0, stream>>>(msg_W2, rmsg_W2, gru_Wih, msg_b2, rmsg_b2, M1, M2, v12);

    int gN64 = (N + 63) / 64;
    enc_gemm<<<gN64, 256, 0, stream>>>(node_features, enc_W, enc_b, h0, N);

    float* hcur = h0; float* hnext = h1;
    dim3 gProj(gN64, 2), gAgg((N + 3) / 4, 2);
    for (int l = 0; l < 3; ++l) {
        proj_kernel<<<gProj, 256, 0, stream>>>(hcur, msg_W1 + l * 6144, msg_b1 + l * 96,
                                               rmsg_W1 + l * 6144, rmsg_b1 + l * 96,
                                               PaF, PbF, PaR, PbR, N);
        agg_bf16<<<gAgg, 256, 0, stream>>>(off_to, list_to, off_from, list_from,
                                           PaF, PaR, PbF, PbR, N);
        gru2_kernel<<<gN64, 512, 0, stream>>>(PbF, PbR, M1 + l * 9216, M2 + l * 9216, v12 + l * 192,
                                              off_to, off_from, hcur, WhhT + l * 3072,
                                              gru_bih + l * 96, gru_bhh + l * 96, hnext, N);
        float* t = hcur; hcur = hnext; hnext = t;
    }

    const int chunk = 32;
    graph_agg<<<(N + chunk - 1) / chunk, 128, 0, stream>>>(hcur, agg_W1, agg_b1, graph_idx, gs, N, chunk);
    final_gemm<<<NG, 128, 0, stream>>>(gs, agg_W2, agg_b2, out);
}

// Round 13
// 785.223 us; speedup vs baseline: 3.0688x; 3.0688x over previous
//
#include <hip/hip_runtime.h>

#define SB 512  // scan tile size

__device__ inline unsigned short f2bf(float f) {
    unsigned u = __float_as_uint(f);
    unsigned r = (u + 0x7fffu + ((u >> 16) & 1u)) >> 16;   // round-nearest-even
    return (unsigned short)r;
}

// ---------------- CSR build (rank captured in count pass; fill is atomic-free) ----------------
__global__ void count_rank_kernel(const int* __restrict__ from_idx, const int* __restrict__ to_idx,
                                  int* __restrict__ cnt_to, int* __restrict__ cnt_from,
                                  int* __restrict__ rank_to, int* __restrict__ rank_from, int E) {
    int e = blockIdx.x * blockDim.x + threadIdx.x;
    if (e >= E) return;
    int f = from_idx[e], t = to_idx[e];
    rank_to[e] = atomicAdd(&cnt_to[t], 1);
    rank_from[e] = atomicAdd(&cnt_from[f], 1);
}

// ---- hierarchical scan: A) block sums, B) scan of block sums, C) block scan + base ----
__global__ void __launch_bounds__(SB) scanA_kernel(const int* __restrict__ cnt_to,
                                                   const int* __restrict__ cnt_from,
                                                   int* __restrict__ bsum, int nblk, int N) {
    const int* cnt = blockIdx.y ? cnt_from : cnt_to;
    __shared__ int s[SB];
    int tid = threadIdx.x;
    int i = blockIdx.x * SB + tid;
    s[tid] = (i < N) ? cnt[i] : 0;
    __syncthreads();
    for (int d = SB / 2; d > 0; d >>= 1) {
        if (tid < d) s[tid] += s[tid + d];
        __syncthreads();
    }
    if (tid == 0) bsum[blockIdx.y * nblk + blockIdx.x] = s[0];
}

__global__ void scanB_kernel(int* __restrict__ bsum, int* __restrict__ bbase,
                             int* __restrict__ off_to, int* __restrict__ off_from,
                             int nblk, int N) {
    int tid = threadIdx.x;
    if (tid < 2) {
        const int* bs = bsum + tid * nblk;
        int* bb = bbase + tid * nblk;
        int run = 0;
        for (int i = 0; i < nblk; ++i) { bb[i] = run; run += bs[i]; }
        if (tid == 0) off_to[N] = run; else off_from[N] = run;
    }
}

__global__ void __launch_bounds__(SB) scanC_kernel(const int* __restrict__ cnt_to,
                                                   const int* __restrict__ cnt_from,
                                                   const int* __restrict__ bbase,
                                                   int* __restrict__ off_to, int* __restrict__ off_from,
                                                   int nblk, int N) {
    const int* cnt = blockIdx.y ? cnt_from : cnt_to;
    int* off = blockIdx.y ? off_from : off_to;
    __shared__ int s[SB];
    int tid = threadIdx.x;
    int i = blockIdx.x * SB + tid;
    int v = (i < N) ? cnt[i] : 0;
    s[tid] = v;
    __syncthreads();
    for (int d = 1; d < SB; d <<= 1) {
        int t = s[tid];
        int add = (tid >= d) ? s[tid - d] : 0;
        __syncthreads();
        s[tid] = t + add;
        __syncthreads();
    }
    if (i < N) off[i] = s[tid] - v + bbase[blockIdx.y * nblk + blockIdx.x];
}

__global__ void fill_kernel(const int* __restrict__ from_idx, const int* __restrict__ to_idx,
                            const int* __restrict__ off_to, const int* __restrict__ off_from,
                            const int* __restrict__ rank_to, const int* __restrict__ rank_from,
                            int* __restrict__ list_to, int* __restrict__ list_from, int E) {
    int e = blockIdx.x * blockDim.x + threadIdx.x;
    if (e >= E) return;
    int f = from_idx[e], t = to_idx[e];
    list_to[off_to[t] + rank_to[e]] = f;
    list_from[off_from[f] + rank_from[e]] = t;
}

// ---------------- Whh transpose ----------------
__global__ void transpose_whh(const float* __restrict__ Whh, float* __restrict__ WhhT) {
    int idx = blockIdx.x * 256 + threadIdx.x;
    if (idx >= 3 * 32 * 96) return;
    int l = idx / 3072, r = idx % 3072;
    int j = r / 96, k = r % 96;
    WhhT[idx] = Whh[l * 3072 + k * 32 + j];
}

// ---------------- compose: M1 = W2 @ Wih^T, M2 = rW2 @ Wih^T, v = b @ Wih^T ----------------
__global__ void compose_kernel(const float* __restrict__ W2, const float* __restrict__ rW2,
                               const float* __restrict__ Wih,
                               const float* __restrict__ b2, const float* __restrict__ rb2,
                               float* __restrict__ M1, float* __restrict__ M2,
                               float* __restrict__ v12) {
    int l = blockIdx.x / 97, j = blockIdx.x % 97;
    int k = threadIdx.x;  // 96
    const float* wih = Wih + l * 9216 + k * 96;
    if (j < 96) {
        const float* w2  = W2 + l * 9216 + j * 96;
        const float* rw2 = rW2 + l * 9216 + j * 96;
        float a1 = 0.f, a2 = 0.f;
        for (int m = 0; m < 96; ++m) {
            float wv = wih[m];
            a1 = fmaf(w2[m], wv, a1);
            a2 = fmaf(rw2[m], wv, a2);
        }
        M1[l * 9216 + j * 96 + k] = a1;
        M2[l * 9216 + j * 96 + k] = a2;
    } else {
        const float* bb = b2 + l * 96;
        const float* rbb = rb2 + l * 96;
        float a1 = 0.f, a2 = 0.f;
        for (int m = 0; m < 96; ++m) {
            float wv = wih[m];
            a1 = fmaf(bb[m], wv, a1);
            a2 = fmaf(rbb[m], wv, a2);
        }
        v12[l * 192 + k] = a1;
        v12[l * 192 + 96 + k] = a2;
    }
}

// ---------------- encoder: h = IN@W + b (r10 layout: stride-33, b32 reads, 0 conflicts) ---------
__global__ void __launch_bounds__(256) enc_gemm(const float* __restrict__ IN,
                                                const float* __restrict__ W, const float* __restrict__ bias,
                                                float* __restrict__ OUT, int N) {
    __shared__ float tile[64][33];
    int n0 = blockIdx.x * 64, tid = threadIdx.x;
    for (int idx = tid; idx < 64 * 32; idx += 256) {
        int r = idx >> 5, c = idx & 31;
        int n = n0 + r;
        tile[r][c] = (n < N) ? IN[(long)n * 32 + c] : 0.f;
    }
    __syncthreads();
    int lane = tid & 63;
    int w = __builtin_amdgcn_readfirstlane(tid >> 6);
    float acc[8] = {0};
    const float* Wp = W + w * 8;
#pragma unroll 4
    for (int j = 0; j < 32; ++j) {
        float a = tile[lane][j];
#pragma unroll
        for (int c = 0; c < 8; ++c) acc[c] = fmaf(a, Wp[j * 32 + c], acc[c]);
    }
    int n = n0 + lane;
    if (n >= N) return;
    float* outp = OUT + (long)n * 32 + w * 8;
#pragma unroll
    for (int c = 0; c < 8; ++c) outp[c] = acc[c] + bias[w * 8 + c];
}

// ---------------- projections (stride-33 b32 tile; ds_reads batched 8 to cut lgkm drains) -------
__global__ void __launch_bounds__(256) proj_kernel(
    const float* __restrict__ h,
    const float* __restrict__ W1f, const float* __restrict__ b1f,
    const float* __restrict__ W1r, const float* __restrict__ b1r,
    unsigned* __restrict__ PaFu, float* __restrict__ PbF,
    unsigned* __restrict__ PaRu, float* __restrict__ PbR, int N)
{
    const float* W1 = blockIdx.y ? W1r : W1f;
    const float* b1 = blockIdx.y ? b1r : b1f;
    unsigned* PaU = blockIdx.y ? PaRu : PaFu;
    float* Pb = blockIdx.y ? PbR : PbF;
    __shared__ float tile[64][33];
    int n0 = blockIdx.x * 64, tid = threadIdx.x;
    for (int idx = tid; idx < 64 * 32; idx += 256) {
        int r = idx >> 5, c = idx & 31;
        int n = n0 + r;
        tile[r][c] = (n < N) ? h[(long)n * 32 + c] : 0.f;
    }
    __syncthreads();
    int lane = tid & 63;
    int w = __builtin_amdgcn_readfirstlane(tid >> 6);
    int c0 = w * 48;
    const float* Wp = (c0 < 96) ? (W1 + c0) : (W1 + 32 * 96 + (c0 - 96));
    float acc[48];
#pragma unroll
    for (int c = 0; c < 48; ++c) acc[c] = 0.f;
    for (int jt = 0; jt < 32; jt += 8) {        // batch LDS reads, then pure s_load+FMA phase
        float a[8];
#pragma unroll
        for (int u = 0; u < 8; ++u) a[u] = tile[lane][jt + u];
#pragma unroll
        for (int u = 0; u < 8; ++u)
#pragma unroll
            for (int c = 0; c < 48; ++c) acc[c] = fmaf(a[u], Wp[(jt + u) * 96 + c], acc[c]);
    }
    int n = n0 + lane;
    if (n >= N) return;
    if (c0 < 96) {
        unsigned* pap = PaU + (long)n * 48 + (c0 >> 1);
#pragma unroll
        for (int c = 0; c < 24; ++c)
            pap[c] = (unsigned)f2bf(acc[2 * c]) | ((unsigned)f2bf(acc[2 * c + 1]) << 16);
    } else {
        float* outp = Pb + (long)n * 96 + (c0 - 96);
#pragma unroll
        for (int c = 0; c < 48; ++c) outp[c] = acc[c] + b1[c0 - 96 + c];
    }
}

// ---------------- edge aggregation: 8 gathers in flight ----------------
__global__ void __launch_bounds__(256) agg_bf16(
    const int* __restrict__ offF, const int* __restrict__ listF,
    const int* __restrict__ offR, const int* __restrict__ listR,
    const unsigned* __restrict__ PaF, const unsigned* __restrict__ PaR,
    float* PbF, float* PbR, int N)
{
    const int* off; const int* list; const unsigned* Pa; float* Pb;
    if (blockIdx.y == 0) { off = offF; list = listF; Pa = PaF; Pb = PbF; }
    else                 { off = offR; list = listR; Pa = PaR; Pb = PbR; }
    int n = __builtin_amdgcn_readfirstlane((blockIdx.x * 256 + threadIdx.x) >> 6);
    int lane = threadIdx.x & 63;
    if (n >= N) return;
    int li = (lane < 48) ? lane : 47;
    bool act = lane < 48;
    long pbase = (long)n * 96 + 2 * li;
    float sx = 0.f, sy = 0.f;
    if (act) { float2 s = *(const float2*)(Pb + pbase); sx = s.x; sy = s.y; }
    float a0 = 0.f, a1 = 0.f;
    int beg = off[n], end = off[n + 1];
    int i = beg;
    for (; i + 8 <= end; i += 8) {              // 8 gathers in flight
        unsigned u[8];
#pragma unroll
        for (int q = 0; q < 8; ++q) u[q] = Pa[(long)list[i + q] * 48 + li];
#pragma unroll
        for (int q = 0; q < 8; ++q) {
            a0 += fmaxf(__uint_as_float(u[q] << 16) + sx, 0.f);
            a1 += fmaxf(__uint_as_float(u[q] & 0xffff0000u) + sy, 0.f);
        }
    }
    for (; i < end; ++i) {
        unsigned u = Pa[(long)list[i] * 48 + li];
        a0 += fmaxf(__uint_as_float(u << 16) + sx, 0.f);
        a1 += fmaxf(__uint_as_float(u & 0xffff0000u) + sy, 0.f);
    }
    if (act) { *(float2*)(Pb + pbase) = make_float2(a0, a1); }
}

// ---------------- fused gates+GRU (r10 structure; ds_reads batched 8 to cut lgkm drains) -------
// stride-97 b32 LDS reads: ==1 mod 32, zero bank conflicts (verified r10).
__global__ void __launch_bounds__(512) gru2_kernel(
    const float* __restrict__ AF, const float* __restrict__ AR,
    const float* __restrict__ M1, const float* __restrict__ M2,
    const float* __restrict__ v12,
    const int* __restrict__ offF, const int* __restrict__ offR,
    const float* __restrict__ h, const float* __restrict__ WhhT,
    const float* __restrict__ bih, const float* __restrict__ bhh,
    float* __restrict__ hout, int N)
{
    __shared__ float buf[64 * 97];              // AF -> AR staging (24.8 KB)
    __shared__ float ht[64][33];                // 8.4 KB
    int n0 = blockIdx.x * 64, tid = threadIdx.x;
    int lane = tid & 63;
    int w = __builtin_amdgcn_readfirstlane(tid >> 6);   // 0..7
    int w4 = w * 4;

    for (int idx = tid; idx < 64 * 96; idx += 512) {
        int r = idx / 96, c = idx % 96;
        int nn = n0 + r;
        buf[r * 97 + c] = (nn < N) ? AF[(long)nn * 96 + c] : 0.f;
    }
    for (int idx = tid; idx < 64 * 32; idx += 512) {
        int r = idx >> 5, c = idx & 31;
        int nn = n0 + r;
        ht[r][c] = (nn < N) ? h[(long)nn * 32 + c] : 0.f;
    }
    __syncthreads();

    float acc[12];
#pragma unroll
    for (int c = 0; c < 12; ++c) acc[c] = 0.f;
    const float* M1w = M1 + w4;
    for (int jt = 0; jt < 96; jt += 8) {        // batch 8 ds_reads, then pure s_load+FMA
        float a[8];
#pragma unroll
        for (int u = 0; u < 8; ++u) a[u] = buf[lane * 97 + jt + u];
#pragma unroll
        for (int u = 0; u < 8; ++u) {
            const float* Wr = M1w + (jt + u) * 96;
#pragma unroll
            for (int g = 0; g < 3; ++g)
#pragma unroll
                for (int i = 0; i < 4; ++i)
                    acc[g * 4 + i] = fmaf(a[u], Wr[g * 32 + i], acc[g * 4 + i]);
        }
    }
    __syncthreads();                            // phase1 reads done; restage AR
    for (int idx = tid; idx < 64 * 96; idx += 512) {
        int r = idx / 96, c = idx % 96;
        int nn = n0 + r;
        buf[r * 97 + c] = (nn < N) ? AR[(long)nn * 96 + c] : 0.f;
    }
    __syncthreads();
    const float* M2w = M2 + w4;
    for (int jt = 0; jt < 96; jt += 8) {
        float a[8];
#pragma unroll
        for (int u = 0; u < 8; ++u) a[u] = buf[lane * 97 + jt + u];
#pragma unroll
        for (int u = 0; u < 8; ++u) {
            const float* Wr = M2w + (jt + u) * 96;
#pragma unroll
            for (int g = 0; g < 3; ++g)
#pragma unroll
                for (int i = 0; i < 4; ++i)
                    acc[g * 4 + i] = fmaf(a[u], Wr[g * 32 + i], acc[g * 4 + i]);
        }
    }
    // degree/bias corrections
    int n = n0 + lane;
    int nb = (n < N) ? n : (N - 1);
    float dF = (float)(offF[nb + 1] - offF[nb]);
    float dR = (float)(offR[nb + 1] - offR[nb]);
    const float* v1 = v12;
    const float* v2 = v12 + 96;
#pragma unroll
    for (int g = 0; g < 3; ++g)
#pragma unroll
        for (int i = 0; i < 4; ++i) {
            int col = g * 32 + w4 + i;
            acc[g * 4 + i] += dF * v1[col] + dR * v2[col] + bih[col];
        }
    // GH = h @ Whh^T  (gate-aligned cols), batched 8
    float acc2[12];
#pragma unroll
    for (int c = 0; c < 12; ++c) acc2[c] = 0.f;
    for (int jt = 0; jt < 32; jt += 8) {
        float b[8];
#pragma unroll
        for (int u = 0; u < 8; ++u) b[u] = ht[lane][jt + u];
#pragma unroll
        for (int u = 0; u < 8; ++u) {
            const float* Wr = WhhT + (jt + u) * 96 + w4;
#pragma unroll
            for (int g = 0; g < 3; ++g)
#pragma unroll
                for (int i = 0; i < 4; ++i)
                    acc2[g * 4 + i] = fmaf(b[u], Wr[g * 32 + i], acc2[g * 4 + i]);
        }
    }
    if (n < N) {
        float4 o;
        float ov[4];
#pragma unroll
        for (int i = 0; i < 4; ++i) {
            int c0 = w4 + i, c1 = 32 + w4 + i, c2 = 64 + w4 + i;
            float r = 1.f / (1.f + __expf(-(acc[i] + acc2[i] + bhh[c0])));
            float z = 1.f / (1.f + __expf(-(acc[4 + i] + acc2[4 + i] + bhh[c1])));
            float nn = tanhf(acc[8 + i] + r * (acc2[8 + i] + bhh[c2]));
            ov[i] = (1.f - z) * nn + z * ht[lane][w4 + i];
        }
        o.x = ov[0]; o.y = ov[1]; o.z = ov[2]; o.w = ov[3];
        *(float4*)(hout + (long)n * 32 + w4) = o;
    }
}

// ---------------- graph aggregator: weights hoisted to registers, chunk=32 ----------------
__global__ void __launch_bounds__(128) graph_agg(const float* __restrict__ h, const float* __restrict__ W1,
                          const float* __restrict__ b1, const int* __restrict__ gidx,
                          float* __restrict__ gs, int N, int chunk) {
    int k = threadIdx.x;  // 128
    int n_start = blockIdx.x * chunk;
    if (n_start >= N) return;
    int n_end = min(n_start + chunk, N);
    float w1[32], w2[32];
#pragma unroll
    for (int j = 0; j < 32; ++j) {
        w1[j] = W1[j * 256 + k];
        w2[j] = W1[j * 256 + 128 + k];
    }
    float bb1 = b1[k], bb2 = b1[128 + k];
    float acc = 0.f;
    int cur = gidx[n_start];
    for (int n = n_start; n < n_end; ++n) {
        int g = gidx[n];
        if (g != cur) { atomicAdd(&gs[cur * 128 + k], acc); acc = 0.f; cur = g; }
        float g1 = bb1, g2 = bb2;
#pragma unroll
        for (int j = 0; j < 32; ++j) {
            float hv = h[(long)n * 32 + j];
            g1 = fmaf(hv, w1[j], g1);
            g2 = fmaf(hv, w2[j], g2);
        }
        acc += (1.f / (1.f + __expf(-g1))) * g2;
    }
    atomicAdd(&gs[cur * 128 + k], acc);
}

__global__ void final_gemm(const float* __restrict__ gs, const float* __restrict__ W,
                           const float* __restrict__ b, float* __restrict__ out) {
    int g = blockIdx.x, k = threadIdx.x;
    float a = b[k];
#pragma unroll 8
    for (int j = 0; j < 128; ++j) a = fmaf(gs[g * 128 + j], W[j * 128 + k], a);
    out[g * 128 + k] = a;
}

extern "C" void kernel_launch(void* const* d_in, const int* in_sizes, int n_in,
                              void* d_out, int out_size, void* d_ws, size_t ws_size,
                              hipStream_t stream) {
    const float* node_features = (const float*)d_in[0];
    const float* enc_W  = (const float*)d_in[1];
    const float* enc_b  = (const float*)d_in[2];
    const float* msg_W1 = (const float*)d_in[3];
    const float* msg_b1 = (const float*)d_in[4];
    const float* msg_W2 = (const float*)d_in[5];
    const float* msg_b2 = (const float*)d_in[6];
    const float* rmsg_W1 = (const float*)d_in[7];
    const float* rmsg_b1 = (const float*)d_in[8];
    const float* rmsg_W2 = (const float*)d_in[9];
    const float* rmsg_b2 = (const float*)d_in[10];
    const float* gru_Wih = (const float*)d_in[11];
    const float* gru_Whh = (const float*)d_in[12];
    const float* gru_bih = (const float*)d_in[13];
    const float* gru_bhh = (const float*)d_in[14];
    const float* agg_W1 = (const float*)d_in[15];
    const float* agg_b1 = (const float*)d_in[16];
    const float* agg_W2 = (const float*)d_in[17];
    const float* agg_b2 = (const float*)d_in[18];
    const int* from_idx = (const int*)d_in[19];
    const int* to_idx   = (const int*)d_in[20];
    const int* graph_idx = (const int*)d_in[21];

    const int N = in_sizes[0] / 32;
    const int E = in_sizes[19];
    const int NG = out_size / 128;
    float* out = (float*)d_out;

    char* ws = (char*)d_ws;
    auto alloc = [&](size_t b) { void* p = (void*)ws; ws += (b + 255) & ~(size_t)255; return p; };
    int* cnt_to   = (int*)alloc((size_t)N * 4);
    int* cnt_from = (int*)alloc((size_t)N * 4);
    int* off_to   = (int*)alloc((size_t)(N + 1) * 4);
    int* off_from = (int*)alloc((size_t)(N + 1) * 4);
    int* list_to  = (int*)alloc((size_t)E * 4);
    int* list_from= (int*)alloc((size_t)E * 4);
    float* h0  = (float*)alloc((size_t)N * 32 * 4);
    float* h1  = (float*)alloc((size_t)N * 32 * 4);
    unsigned* PaF = (unsigned*)alloc((size_t)N * 48 * 4);
    unsigned* PaR = (unsigned*)alloc((size_t)N * 48 * 4);
    float* PbF = (float*)alloc((size_t)N * 96 * 4);
    float* PbR = (float*)alloc((size_t)N * 96 * 4);
    float* WhhT = (float*)alloc((size_t)3 * 32 * 96 * 4);
    float* M1   = (float*)alloc((size_t)3 * 96 * 96 * 4);
    float* M2   = (float*)alloc((size_t)3 * 96 * 96 * 4);
    float* v12  = (float*)alloc((size_t)3 * 192 * 4);
    float* gs   = (float*)alloc((size_t)NG * 128 * 4);
    const int nblk = (N + SB - 1) / SB;
    int* bsum  = (int*)alloc((size_t)2 * nblk * 4);
    int* bbase = (int*)alloc((size_t)2 * nblk * 4);
    // rank arrays alias Pb buffers (dead before proj writes them)
    int* rank_to   = (int*)PbF;
    int* rank_from = (int*)PbR;

    hipMemsetAsync(cnt_to, 0, (size_t)N * 4, stream);
    hipMemsetAsync(cnt_from, 0, (size_t)N * 4, stream);
    hipMemsetAsync(gs, 0, (size_t)NG * 128 * 4, stream);

    int gE = (E + 255) / 256;
    count_rank_kernel<<<gE, 256, 0, stream>>>(from_idx, to_idx, cnt_to, cnt_from, rank_to, rank_from, E);
    dim3 gScan(nblk, 2);
    scanA_kernel<<<gScan, SB, 0, stream>>>(cnt_to, cnt_from, bsum, nblk, N);
    scanB_kernel<<<1, 64, 0, stream>>>(bsum, bbase, off_to, off_from, nblk, N);
    scanC_kernel<<<gScan, SB, 0, stream>>>(cnt_to, cnt_from, bbase, off_to, off_from, nblk, N);
    fill_kernel<<<gE, 256, 0, stream>>>(from_idx, to_idx, off_to, off_from, rank_to, rank_from,
                                        list_to, list_from, E);

    transpose_whh<<<(3 * 32 * 96 + 255) / 256, 256, 0, stream>>>(gru_Whh, WhhT);
    compose_kernel<<<3 * 97, 96, 0, stream>>>(msg_W2, rmsg_W2, gru_Wih, msg_b2, rmsg_b2, M1, M2, v12);

    int gN64 = (N + 63) / 64;
    enc_gemm<<<gN64, 256, 0, stream>>>(node_features, enc_W, enc_b, h0, N);

    float* hcur = h0; float* hnext = h1;
    dim3 gProj(gN64, 2), gAgg((N + 3) / 4, 2);
    for (int l = 0; l < 3; ++l) {
        proj_kernel<<<gProj, 256, 0, stream>>>(hcur, msg_W1 + l * 6144, msg_b1 + l * 96,
                                               rmsg_W1 + l * 6144, rmsg_b1 + l * 96,
                                               PaF, PbF, PaR, PbR, N);
        agg_bf16<<<gAgg, 256, 0, stream>>>(off_to, list_to, off_from, list_from,
                                           PaF, PaR, PbF, PbR, N);
        gru2_kernel<<<gN64, 512, 0, stream>>>(PbF, PbR, M1 + l * 9216, M2 + l * 9216, v12 + l * 192,
                                              off_to, off_from, hcur, WhhT + l * 3072,
                                              gru_bih + l * 96, gru_bhh + l * 96, hnext, N);
        float* t = hcur; hcur = hnext; hnext = t;
    }

    const int chunk = 32;
    graph_agg<<<(N + chunk - 1) / chunk, 128, 0, stream>>>(hcur, agg_W1, agg_b1, graph_idx, gs, N, chunk);
    final_gemm<<<NG, 128, 0, stream>>>(gs, agg_W2, agg_b2, out);
}

// Round 14
// 529.182 us; speedup vs baseline: 4.5536x; 1.4838x over previous
//
#include <hip/hip_runtime.h>

#define SB 512  // scan tile size

typedef __attribute__((ext_vector_type(8))) short short8;
typedef __attribute__((ext_vector_type(4))) float f32x4;

__device__ inline unsigned short f2bf(float f) {
    unsigned u = __float_as_uint(f);
    unsigned r = (u + 0x7fffu + ((u >> 16) & 1u)) >> 16;   // round-nearest-even
    return (unsigned short)r;
}
__device__ inline unsigned pack2bf(float x, float y) {
    return (unsigned)f2bf(x) | ((unsigned)f2bf(y) << 16);
}

// ---------------- CSR build (rank captured in count pass; fill is atomic-free) ----------------
__global__ void count_rank_kernel(const int* __restrict__ from_idx, const int* __restrict__ to_idx,
                                  int* __restrict__ cnt_to, int* __restrict__ cnt_from,
                                  int* __restrict__ rank_to, int* __restrict__ rank_from, int E) {
    int e = blockIdx.x * blockDim.x + threadIdx.x;
    if (e >= E) return;
    int f = from_idx[e], t = to_idx[e];
    rank_to[e] = atomicAdd(&cnt_to[t], 1);
    rank_from[e] = atomicAdd(&cnt_from[f], 1);
}

// ---- hierarchical scan ----
__global__ void __launch_bounds__(SB) scanA_kernel(const int* __restrict__ cnt_to,
                                                   const int* __restrict__ cnt_from,
                                                   int* __restrict__ bsum, int nblk, int N) {
    const int* cnt = blockIdx.y ? cnt_from : cnt_to;
    __shared__ int s[SB];
    int tid = threadIdx.x;
    int i = blockIdx.x * SB + tid;
    s[tid] = (i < N) ? cnt[i] : 0;
    __syncthreads();
    for (int d = SB / 2; d > 0; d >>= 1) {
        if (tid < d) s[tid] += s[tid + d];
        __syncthreads();
    }
    if (tid == 0) bsum[blockIdx.y * nblk + blockIdx.x] = s[0];
}

__global__ void scanB_kernel(int* __restrict__ bsum, int* __restrict__ bbase,
                             int* __restrict__ off_to, int* __restrict__ off_from,
                             int nblk, int N) {
    int tid = threadIdx.x;
    if (tid < 2) {
        const int* bs = bsum + tid * nblk;
        int* bb = bbase + tid * nblk;
        int run = 0;
        for (int i = 0; i < nblk; ++i) { bb[i] = run; run += bs[i]; }
        if (tid == 0) off_to[N] = run; else off_from[N] = run;
    }
}

__global__ void __launch_bounds__(SB) scanC_kernel(const int* __restrict__ cnt_to,
                                                   const int* __restrict__ cnt_from,
                                                   const int* __restrict__ bbase,
                                                   int* __restrict__ off_to, int* __restrict__ off_from,
                                                   int nblk, int N) {
    const int* cnt = blockIdx.y ? cnt_from : cnt_to;
    int* off = blockIdx.y ? off_from : off_to;
    __shared__ int s[SB];
    int tid = threadIdx.x;
    int i = blockIdx.x * SB + tid;
    int v = (i < N) ? cnt[i] : 0;
    s[tid] = v;
    __syncthreads();
    for (int d = 1; d < SB; d <<= 1) {
        int t = s[tid];
        int add = (tid >= d) ? s[tid - d] : 0;
        __syncthreads();
        s[tid] = t + add;
        __syncthreads();
    }
    if (i < N) off[i] = s[tid] - v + bbase[blockIdx.y * nblk + blockIdx.x];
}

__global__ void fill_kernel(const int* __restrict__ from_idx, const int* __restrict__ to_idx,
                            const int* __restrict__ off_to, const int* __restrict__ off_from,
                            const int* __restrict__ rank_to, const int* __restrict__ rank_from,
                            int* __restrict__ list_to, int* __restrict__ list_from, int E) {
    int e = blockIdx.x * blockDim.x + threadIdx.x;
    if (e >= E) return;
    int f = from_idx[e], t = to_idx[e];
    list_to[off_to[t] + rank_to[e]] = f;
    list_from[off_from[f] + rank_from[e]] = t;
}

// ---------------- Whh transpose (fp32, feeds repack) ----------------
__global__ void transpose_whh(const float* __restrict__ Whh, float* __restrict__ WhhT) {
    int idx = blockIdx.x * 256 + threadIdx.x;
    if (idx >= 3 * 32 * 96) return;
    int l = idx / 3072, r = idx % 3072;
    int j = r / 96, k = r % 96;
    WhhT[idx] = Whh[l * 3072 + k * 32 + j];
}

// ---------------- compose: M1 = W2 @ Wih^T, M2 = rW2 @ Wih^T, v = b @ Wih^T ----------------
__global__ void compose_kernel(const float* __restrict__ W2, const float* __restrict__ rW2,
                               const float* __restrict__ Wih,
                               const float* __restrict__ b2, const float* __restrict__ rb2,
                               float* __restrict__ M1, float* __restrict__ M2,
                               float* __restrict__ v12) {
    int l = blockIdx.x / 97, j = blockIdx.x % 97;
    int k = threadIdx.x;  // 96
    const float* wih = Wih + l * 9216 + k * 96;
    if (j < 96) {
        const float* w2  = W2 + l * 9216 + j * 96;
        const float* rw2 = rW2 + l * 9216 + j * 96;
        float a1 = 0.f, a2 = 0.f;
        for (int m = 0; m < 96; ++m) {
            float wv = wih[m];
            a1 = fmaf(w2[m], wv, a1);
            a2 = fmaf(rw2[m], wv, a2);
        }
        M1[l * 9216 + j * 96 + k] = a1;
        M2[l * 9216 + j * 96 + k] = a2;
    } else {
        const float* bb = b2 + l * 96;
        const float* rbb = rb2 + l * 96;
        float a1 = 0.f, a2 = 0.f;
        for (int m = 0; m < 96; ++m) {
            float wv = wih[m];
            a1 = fmaf(bb[m], wv, a1);
            a2 = fmaf(rbb[m], wv, a2);
        }
        v12[l * 192 + k] = a1;
        v12[l * 192 + 96 + k] = a2;
    }
}

// ---------------- repack weights to col-major packed bf16 for MFMA B-fragments ----------------
// M1bc/M2bc: per layer [96 cols][48 words]; Whhbc: per layer [96 cols][16 words]
__global__ void repack_kernel(const float* __restrict__ M1, const float* __restrict__ M2,
                              const float* __restrict__ WhhT,
                              unsigned* __restrict__ M1bc, unsigned* __restrict__ M2bc,
                              unsigned* __restrict__ Whhbc) {
    int idx = blockIdx.x * 256 + threadIdx.x;
    if (idx < 13824) {
        int l = idx / 4608, r = idx % 4608, c = r / 48, wd = r % 48;
        const float* src = M1 + l * 9216;
        M1bc[idx] = pack2bf(src[(2 * wd) * 96 + c], src[(2 * wd + 1) * 96 + c]);
    } else if (idx < 27648) {
        int j = idx - 13824;
        int l = j / 4608, r = j % 4608, c = r / 48, wd = r % 48;
        const float* src = M2 + l * 9216;
        M2bc[j] = pack2bf(src[(2 * wd) * 96 + c], src[(2 * wd + 1) * 96 + c]);
    } else if (idx < 27648 + 4608) {
        int j = idx - 27648;
        int l = j / 1536, r = j % 1536, c = r / 16, wd = r % 16;
        const float* src = WhhT + l * 3072;
        Whhbc[j] = pack2bf(src[(2 * wd) * 96 + c], src[(2 * wd + 1) * 96 + c]);
    }
}

// ---------------- h -> packed bf16 mirror ----------------
__global__ void h2bf_kernel(const float* __restrict__ h, unsigned* __restrict__ hb, int n16) {
    int i = blockIdx.x * 256 + threadIdx.x;
    if (i >= n16) return;
    float2 v = *(const float2*)(h + (size_t)i * 2);
    hb[i] = pack2bf(v.x, v.y);
}

// ---------------- encoder: h = IN@W + b (r10 form) ----------------
__global__ void __launch_bounds__(256) enc_gemm(const float* __restrict__ IN,
                                                const float* __restrict__ W, const float* __restrict__ bias,
                                                float* __restrict__ OUT, int N) {
    __shared__ float tile[64][33];
    int n0 = blockIdx.x * 64, tid = threadIdx.x;
    for (int idx = tid; idx < 64 * 32; idx += 256) {
        int r = idx >> 5, c = idx & 31;
        int n = n0 + r;
        tile[r][c] = (n < N) ? IN[(long)n * 32 + c] : 0.f;
    }
    __syncthreads();
    int lane = tid & 63;
    int w = __builtin_amdgcn_readfirstlane(tid >> 6);
    float acc[8] = {0};
    const float* Wp = W + w * 8;
#pragma unroll 4
    for (int j = 0; j < 32; ++j) {
        float a = tile[lane][j];
#pragma unroll
        for (int c = 0; c < 8; ++c) acc[c] = fmaf(a, Wp[j * 32 + c], acc[c]);
    }
    int n = n0 + lane;
    if (n >= N) return;
    float* outp = OUT + (long)n * 32 + w * 8;
#pragma unroll
    for (int c = 0; c < 8; ++c) outp[c] = acc[c] + bias[w * 8 + c];
}

// ---------------- projections (r10 form) ----------------
__global__ void __launch_bounds__(256) proj_kernel(
    const float* __restrict__ h,
    const float* __restrict__ W1f, const float* __restrict__ b1f,
    const float* __restrict__ W1r, const float* __restrict__ b1r,
    unsigned* __restrict__ PaFu, float* __restrict__ PbF,
    unsigned* __restrict__ PaRu, float* __restrict__ PbR, int N)
{
    const float* W1 = blockIdx.y ? W1r : W1f;
    const float* b1 = blockIdx.y ? b1r : b1f;
    unsigned* PaU = blockIdx.y ? PaRu : PaFu;
    float* Pb = blockIdx.y ? PbR : PbF;
    __shared__ float tile[64][33];
    int n0 = blockIdx.x * 64, tid = threadIdx.x;
    for (int idx = tid; idx < 64 * 32; idx += 256) {
        int r = idx >> 5, c = idx & 31;
        int n = n0 + r;
        tile[r][c] = (n < N) ? h[(long)n * 32 + c] : 0.f;
    }
    __syncthreads();
    int lane = tid & 63;
    int w = __builtin_amdgcn_readfirstlane(tid >> 6);
    int c0 = w * 48;
    const float* Wp = (c0 < 96) ? (W1 + c0) : (W1 + 32 * 96 + (c0 - 96));
    float acc[48];
#pragma unroll
    for (int c = 0; c < 48; ++c) acc[c] = 0.f;
#pragma unroll 2
    for (int j = 0; j < 32; ++j) {
        float a = tile[lane][j];
#pragma unroll
        for (int c = 0; c < 48; ++c) acc[c] = fmaf(a, Wp[j * 96 + c], acc[c]);
    }
    int n = n0 + lane;
    if (n >= N) return;
    if (c0 < 96) {
        unsigned* pap = PaU + (long)n * 48 + (c0 >> 1);
#pragma unroll
        for (int c = 0; c < 24; ++c)
            pap[c] = pack2bf(acc[2 * c], acc[2 * c + 1]);
    } else {
        float* outp = Pb + (long)n * 96 + (c0 - 96);
#pragma unroll
        for (int c = 0; c < 48; ++c) outp[c] = acc[c] + b1[c0 - 96 + c];
    }
}

// ---------------- edge aggregation: gather bf16 Pa; OUTPUT packed bf16 (AFb/ARb) ----------------
__global__ void __launch_bounds__(256) agg_bf16(
    const int* __restrict__ offF, const int* __restrict__ listF,
    const int* __restrict__ offR, const int* __restrict__ listR,
    const unsigned* __restrict__ PaF, const unsigned* __restrict__ PaR,
    const float* __restrict__ PbF, const float* __restrict__ PbR,
    unsigned* __restrict__ AFb, unsigned* __restrict__ ARb, int N)
{
    const int* off; const int* list; const unsigned* Pa; const float* Pb; unsigned* AB;
    if (blockIdx.y == 0) { off = offF; list = listF; Pa = PaF; Pb = PbF; AB = AFb; }
    else                 { off = offR; list = listR; Pa = PaR; Pb = PbR; AB = ARb; }
    int n = __builtin_amdgcn_readfirstlane((blockIdx.x * 256 + threadIdx.x) >> 6);
    int lane = threadIdx.x & 63;
    if (n >= N) return;
    int li = (lane < 48) ? lane : 47;
    bool act = lane < 48;
    float sx = 0.f, sy = 0.f;
    if (act) { float2 s = *(const float2*)(Pb + (long)n * 96 + 2 * li); sx = s.x; sy = s.y; }
    float a0 = 0.f, a1 = 0.f;
    int beg = off[n], end = off[n + 1];
    int i = beg;
    for (; i + 8 <= end; i += 8) {              // 8 gathers in flight
        unsigned u[8];
#pragma unroll
        for (int q = 0; q < 8; ++q) u[q] = Pa[(long)list[i + q] * 48 + li];
#pragma unroll
        for (int q = 0; q < 8; ++q) {
            a0 += fmaxf(__uint_as_float(u[q] << 16) + sx, 0.f);
            a1 += fmaxf(__uint_as_float(u[q] & 0xffff0000u) + sy, 0.f);
        }
    }
    for (; i < end; ++i) {
        unsigned u = Pa[(long)list[i] * 48 + li];
        a0 += fmaxf(__uint_as_float(u << 16) + sx, 0.f);
        a1 += fmaxf(__uint_as_float(u & 0xffff0000u) + sy, 0.f);
    }
    if (act) AB[(long)n * 48 + li] = pack2bf(a0, a1);   // cols 2li, 2li+1
}

// ---------------- gru3: MFMA gates. GI = AF@M1 + AR@M2 (K=96), GH = h@WhhT (K=32) ----------------
// Wave w: node-tile nt=w>>1 (16 nodes), col-group cg=w&1 -> gate-aligned cols {g*32 + cg*16 + 0..15}.
// A-frag: row = lane&15, k = (lane>>4)*8+e.  B-frag: col = lane&15, same k.  D: col=lane&15,
// row=(lane>>4)*4+reg (m89-verified). No LDS, no barriers, no SGPR weight streaming.
__global__ void __launch_bounds__(512) gru3_kernel(
    const unsigned* __restrict__ AFb, const unsigned* __restrict__ ARb,
    const unsigned* __restrict__ M1bc, const unsigned* __restrict__ M2bc,
    const unsigned* __restrict__ Whhbc,
    const float* __restrict__ v12,
    const int* __restrict__ offF, const int* __restrict__ offR,
    const float* __restrict__ h, const unsigned* __restrict__ hb,
    const float* __restrict__ bih, const float* __restrict__ bhh,
    float* __restrict__ hout, int N)
{
    int tid = threadIdx.x;
    int lane = tid & 63;
    int w = __builtin_amdgcn_readfirstlane(tid >> 6);   // 0..7
    int nt = w >> 1, cg = w & 1;
    int kgrp = lane >> 4;                                // 0..3
    int c = cg * 16 + (lane & 15);                       // col within a gate (0..31)
    int ntile = blockIdx.x * 64 + nt * 16;
    int arow = ntile + (lane & 15);
    long arc = (arow < N) ? arow : (N - 1);

    f32x4 acc[3]; f32x4 gh[3];
#pragma unroll
    for (int g = 0; g < 3; ++g) { acc[g] = (f32x4){0.f,0.f,0.f,0.f}; gh[g] = (f32x4){0.f,0.f,0.f,0.f}; }

    const unsigned* afp = AFb + arc * 48 + kgrp * 4;
    const unsigned* arp = ARb + arc * 48 + kgrp * 4;
#pragma unroll
    for (int k0 = 0; k0 < 3; ++k0) {
        short8 a = *(const short8*)(afp + k0 * 16);
#pragma unroll
        for (int g = 0; g < 3; ++g) {
            int col = g * 32 + c;
            short8 b = *(const short8*)(M1bc + (long)col * 48 + k0 * 16 + kgrp * 4);
            acc[g] = __builtin_amdgcn_mfma_f32_16x16x32_bf16(a, b, acc[g], 0, 0, 0);
        }
    }
#pragma unroll
    for (int k0 = 0; k0 < 3; ++k0) {
        short8 a = *(const short8*)(arp + k0 * 16);
#pragma unroll
        for (int g = 0; g < 3; ++g) {
            int col = g * 32 + c;
            short8 b = *(const short8*)(M2bc + (long)col * 48 + k0 * 16 + kgrp * 4);
            acc[g] = __builtin_amdgcn_mfma_f32_16x16x32_bf16(a, b, acc[g], 0, 0, 0);
        }
    }
    {
        short8 ha = *(const short8*)(hb + arc * 16 + kgrp * 4);
#pragma unroll
        for (int g = 0; g < 3; ++g) {
            int col = g * 32 + c;
            short8 b = *(const short8*)(Whhbc + (long)col * 16 + kgrp * 4);
            gh[g] = __builtin_amdgcn_mfma_f32_16x16x32_bf16(ha, b, gh[g], 0, 0, 0);
        }
    }

    // epilogue: lane owns nodes ntile + kgrp*4 + i (i=0..3) at col c (per gate)
    float v1r[3], v2r[3], bihv[3], bhhv[3];
#pragma unroll
    for (int g = 0; g < 3; ++g) {
        int col = g * 32 + c;
        v1r[g] = v12[col]; v2r[g] = v12[96 + col];
        bihv[g] = bih[col]; bhhv[g] = bhh[col];
    }
    int nbase = ntile + kgrp * 4;
#pragma unroll
    for (int i = 0; i < 4; ++i) {
        int n = nbase + i;
        if (n < N) {
            float dF = (float)(offF[n + 1] - offF[n]);
            float dR = (float)(offR[n + 1] - offR[n]);
            float gir = acc[0][i] + dF * v1r[0] + dR * v2r[0] + bihv[0];
            float giz = acc[1][i] + dF * v1r[1] + dR * v2r[1] + bihv[1];
            float gin = acc[2][i] + dF * v1r[2] + dR * v2r[2] + bihv[2];
            float r = 1.f / (1.f + __expf(-(gir + gh[0][i] + bhhv[0])));
            float z = 1.f / (1.f + __expf(-(giz + gh[1][i] + bhhv[1])));
            float nn = tanhf(gin + r * (gh[2][i] + bhhv[2]));
            float hv = h[(long)n * 32 + c];
            hout[(long)n * 32 + c] = (1.f - z) * nn + z * hv;
        }
    }
}

// ---------------- graph aggregator ----------------
__global__ void __launch_bounds__(128) graph_agg(const float* __restrict__ h, const float* __restrict__ W1,
                          const float* __restrict__ b1, const int* __restrict__ gidx,
                          float* __restrict__ gs, int N, int chunk) {
    int k = threadIdx.x;  // 128
    int n_start = blockIdx.x * chunk;
    if (n_start >= N) return;
    int n_end = min(n_start + chunk, N);
    float w1[32], w2[32];
#pragma unroll
    for (int j = 0; j < 32; ++j) {
        w1[j] = W1[j * 256 + k];
        w2[j] = W1[j * 256 + 128 + k];
    }
    float bb1 = b1[k], bb2 = b1[128 + k];
    float acc = 0.f;
    int cur = gidx[n_start];
    for (int n = n_start; n < n_end; ++n) {
        int g = gidx[n];
        if (g != cur) { atomicAdd(&gs[cur * 128 + k], acc); acc = 0.f; cur = g; }
        float g1 = bb1, g2 = bb2;
#pragma unroll
        for (int j = 0; j < 32; ++j) {
            float hv = h[(long)n * 32 + j];
            g1 = fmaf(hv, w1[j], g1);
            g2 = fmaf(hv, w2[j], g2);
        }
        acc += (1.f / (1.f + __expf(-g1))) * g2;
    }
    atomicAdd(&gs[cur * 128 + k], acc);
}

__global__ void final_gemm(const float* __restrict__ gs, const float* __restrict__ W,
                           const float* __restrict__ b, float* __restrict__ out) {
    int g = blockIdx.x, k = threadIdx.x;
    float a = b[k];
#pragma unroll 8
    for (int j = 0; j < 128; ++j) a = fmaf(gs[g * 128 + j], W[j * 128 + k], a);
    out[g * 128 + k] = a;
}

extern "C" void kernel_launch(void* const* d_in, const int* in_sizes, int n_in,
                              void* d_out, int out_size, void* d_ws, size_t ws_size,
                              hipStream_t stream) {
    const float* node_features = (const float*)d_in[0];
    const float* enc_W  = (const float*)d_in[1];
    const float* enc_b  = (const float*)d_in[2];
    const float* msg_W1 = (const float*)d_in[3];
    const float* msg_b1 = (const float*)d_in[4];
    const float* msg_W2 = (const float*)d_in[5];
    const float* msg_b2 = (const float*)d_in[6];
    const float* rmsg_W1 = (const float*)d_in[7];
    const float* rmsg_b1 = (const float*)d_in[8];
    const float* rmsg_W2 = (const float*)d_in[9];
    const float* rmsg_b2 = (const float*)d_in[10];
    const float* gru_Wih = (const float*)d_in[11];
    const float* gru_Whh = (const float*)d_in[12];
    const float* gru_bih = (const float*)d_in[13];
    const float* gru_bhh = (const float*)d_in[14];
    const float* agg_W1 = (const float*)d_in[15];
    const float* agg_b1 = (const float*)d_in[16];
    const float* agg_W2 = (const float*)d_in[17];
    const float* agg_b2 = (const float*)d_in[18];
    const int* from_idx = (const int*)d_in[19];
    const int* to_idx   = (const int*)d_in[20];
    const int* graph_idx = (const int*)d_in[21];

    const int N = in_sizes[0] / 32;
    const int E = in_sizes[19];
    const int NG = out_size / 128;
    float* out = (float*)d_out;

    char* ws = (char*)d_ws;
    auto alloc = [&](size_t b) { void* p = (void*)ws; ws += (b + 255) & ~(size_t)255; return p; };
    int* cnt_to   = (int*)alloc((size_t)N * 4);
    int* cnt_from = (int*)alloc((size_t)N * 4);
    int* off_to   = (int*)alloc((size_t)(N + 1) * 4);
    int* off_from = (int*)alloc((size_t)(N + 1) * 4);
    int* list_to  = (int*)alloc((size_t)E * 4);
    int* list_from= (int*)alloc((size_t)E * 4);
    float* h0  = (float*)alloc((size_t)N * 32 * 4);
    float* h1  = (float*)alloc((size_t)N * 32 * 4);
    unsigned* PaF = (unsigned*)alloc((size_t)N * 48 * 4);
    unsigned* PaR = (unsigned*)alloc((size_t)N * 48 * 4);
    float* PbF = (float*)alloc((size_t)N * 96 * 4);
    float* PbR = (float*)alloc((size_t)N * 96 * 4);
    unsigned* AFb = (unsigned*)alloc((size_t)N * 48 * 4);
    unsigned* ARb = (unsigned*)alloc((size_t)N * 48 * 4);
    unsigned* hb  = (unsigned*)alloc((size_t)N * 16 * 4);
    float* WhhT = (float*)alloc((size_t)3 * 32 * 96 * 4);
    float* M1   = (float*)alloc((size_t)3 * 96 * 96 * 4);
    float* M2   = (float*)alloc((size_t)3 * 96 * 96 * 4);
    float* v12  = (float*)alloc((size_t)3 * 192 * 4);
    unsigned* M1bc = (unsigned*)alloc((size_t)13824 * 4);
    unsigned* M2bc = (unsigned*)alloc((size_t)13824 * 4);
    unsigned* Whhbc = (unsigned*)alloc((size_t)4608 * 4);
    float* gs   = (float*)alloc((size_t)NG * 128 * 4);
    const int nblk = (N + SB - 1) / SB;
    int* bsum  = (int*)alloc((size_t)2 * nblk * 4);
    int* bbase = (int*)alloc((size_t)2 * nblk * 4);
    // rank arrays alias Pb buffers (dead before proj writes them)
    int* rank_to   = (int*)PbF;
    int* rank_from = (int*)PbR;

    hipMemsetAsync(cnt_to, 0, (size_t)N * 4, stream);
    hipMemsetAsync(cnt_from, 0, (size_t)N * 4, stream);
    hipMemsetAsync(gs, 0, (size_t)NG * 128 * 4, stream);

    int gE = (E + 255) / 256;
    count_rank_kernel<<<gE, 256, 0, stream>>>(from_idx, to_idx, cnt_to, cnt_from, rank_to, rank_from, E);
    dim3 gScan(nblk, 2);
    scanA_kernel<<<gScan, SB, 0, stream>>>(cnt_to, cnt_from, bsum, nblk, N);
    scanB_kernel<<<1, 64, 0, stream>>>(bsum, bbase, off_to, off_from, nblk, N);
    scanC_kernel<<<gScan, SB, 0, stream>>>(cnt_to, cnt_from, bbase, off_to, off_from, nblk, N);
    fill_kernel<<<gE, 256, 0, stream>>>(from_idx, to_idx, off_to, off_from, rank_to, rank_from,
                                        list_to, list_from, E);

    transpose_whh<<<(3 * 32 * 96 + 255) / 256, 256, 0, stream>>>(gru_Whh, WhhT);
    compose_kernel<<<3 * 97, 96, 0, stream>>>(msg_W2, rmsg_W2, gru_Wih, msg_b2, rmsg_b2, M1, M2, v12);
    repack_kernel<<<(27648 + 4608 + 255) / 256, 256, 0, stream>>>(M1, M2, WhhT, M1bc, M2bc, Whhbc);

    int gN64 = (N + 63) / 64;
    enc_gemm<<<gN64, 256, 0, stream>>>(node_features, enc_W, enc_b, h0, N);
    h2bf_kernel<<<(N * 16 + 255) / 256, 256, 0, stream>>>(h0, hb, N * 16);

    float* hcur = h0; float* hnext = h1;
    dim3 gProj(gN64, 2), gAgg((N + 3) / 4, 2);
    for (int l = 0; l < 3; ++l) {
        proj_kernel<<<gProj, 256, 0, stream>>>(hcur, msg_W1 + l * 6144, msg_b1 + l * 96,
                                               rmsg_W1 + l * 6144, rmsg_b1 + l * 96,
                                               PaF, PbF, PaR, PbR, N);
        agg_bf16<<<gAgg, 256, 0, stream>>>(off_to, list_to, off_from, list_from,
                                           PaF, PaR, PbF, PbR, AFb, ARb, N);
        gru3_kernel<<<gN64, 512, 0, stream>>>(AFb, ARb, M1bc + l * 4608, M2bc + l * 4608,
                                              Whhbc + l * 1536, v12 + l * 192,
                                              off_to, off_from, hcur, hb,
                                              gru_bih + l * 96, gru_bhh + l * 96, hnext, N);
        if (l < 2) h2bf_kernel<<<(N * 16 + 255) / 256, 256, 0, stream>>>(hnext, hb, N * 16);
        float* t = hcur; hcur = hnext; hnext = t;
    }

    const int chunk = 32;
    graph_agg<<<(N + chunk - 1) / chunk, 128, 0, stream>>>(hcur, agg_W1, agg_b1, graph_idx, gs, N, chunk);
    final_gemm<<<NG, 128, 0, stream>>>(gs, agg_W2, agg_b2, out);
}

// Round 15
// 436.393 us; speedup vs baseline: 5.5219x; 1.2126x over previous
//
#include <hip/hip_runtime.h>

#define SB 512  // scan tile size

typedef __attribute__((ext_vector_type(8))) short short8;
typedef __attribute__((ext_vector_type(4))) float f32x4;

__device__ inline unsigned short f2bf(float f) {
    unsigned u = __float_as_uint(f);
    unsigned r = (u + 0x7fffu + ((u >> 16) & 1u)) >> 16;   // round-nearest-even
    return (unsigned short)r;
}
__device__ inline unsigned pack2bf(float x, float y) {
    return (unsigned)f2bf(x) | ((unsigned)f2bf(y) << 16);
}

// ---------------- CSR build (rank captured in count pass; fill is atomic-free) ----------------
__global__ void count_rank_kernel(const int* __restrict__ from_idx, const int* __restrict__ to_idx,
                                  int* __restrict__ cnt_to, int* __restrict__ cnt_from,
                                  int* __restrict__ rank_to, int* __restrict__ rank_from, int E) {
    int e = blockIdx.x * blockDim.x + threadIdx.x;
    if (e >= E) return;
    int f = from_idx[e], t = to_idx[e];
    rank_to[e] = atomicAdd(&cnt_to[t], 1);
    rank_from[e] = atomicAdd(&cnt_from[f], 1);
}

// ---- hierarchical scan ----
__global__ void __launch_bounds__(SB) scanA_kernel(const int* __restrict__ cnt_to,
                                                   const int* __restrict__ cnt_from,
                                                   int* __restrict__ bsum, int nblk, int N) {
    const int* cnt = blockIdx.y ? cnt_from : cnt_to;
    __shared__ int s[SB];
    int tid = threadIdx.x;
    int i = blockIdx.x * SB + tid;
    s[tid] = (i < N) ? cnt[i] : 0;
    __syncthreads();
    for (int d = SB / 2; d > 0; d >>= 1) {
        if (tid < d) s[tid] += s[tid + d];
        __syncthreads();
    }
    if (tid == 0) bsum[blockIdx.y * nblk + blockIdx.x] = s[0];
}

__global__ void scanB_kernel(int* __restrict__ bsum, int* __restrict__ bbase,
                             int* __restrict__ off_to, int* __restrict__ off_from,
                             int nblk, int N) {
    int tid = threadIdx.x;
    if (tid < 2) {
        const int* bs = bsum + tid * nblk;
        int* bb = bbase + tid * nblk;
        int run = 0;
        for (int i = 0; i < nblk; ++i) { bb[i] = run; run += bs[i]; }
        if (tid == 0) off_to[N] = run; else off_from[N] = run;
    }
}

__global__ void __launch_bounds__(SB) scanC_kernel(const int* __restrict__ cnt_to,
                                                   const int* __restrict__ cnt_from,
                                                   const int* __restrict__ bbase,
                                                   int* __restrict__ off_to, int* __restrict__ off_from,
                                                   int nblk, int N) {
    const int* cnt = blockIdx.y ? cnt_from : cnt_to;
    int* off = blockIdx.y ? off_from : off_to;
    __shared__ int s[SB];
    int tid = threadIdx.x;
    int i = blockIdx.x * SB + tid;
    int v = (i < N) ? cnt[i] : 0;
    s[tid] = v;
    __syncthreads();
    for (int d = 1; d < SB; d <<= 1) {
        int t = s[tid];
        int add = (tid >= d) ? s[tid - d] : 0;
        __syncthreads();
        s[tid] = t + add;
        __syncthreads();
    }
    if (i < N) off[i] = s[tid] - v + bbase[blockIdx.y * nblk + blockIdx.x];
}

__global__ void fill_kernel(const int* __restrict__ from_idx, const int* __restrict__ to_idx,
                            const int* __restrict__ off_to, const int* __restrict__ off_from,
                            const int* __restrict__ rank_to, const int* __restrict__ rank_from,
                            int* __restrict__ list_to, int* __restrict__ list_from, int E) {
    int e = blockIdx.x * blockDim.x + threadIdx.x;
    if (e >= E) return;
    int f = from_idx[e], t = to_idx[e];
    list_to[off_to[t] + rank_to[e]] = f;
    list_from[off_from[f] + rank_from[e]] = t;
}

// ---------------- Whh transpose (fp32, feeds repack) ----------------
__global__ void transpose_whh(const float* __restrict__ Whh, float* __restrict__ WhhT) {
    int idx = blockIdx.x * 256 + threadIdx.x;
    if (idx >= 3 * 32 * 96) return;
    int l = idx / 3072, r = idx % 3072;
    int j = r / 96, k = r % 96;
    WhhT[idx] = Whh[l * 3072 + k * 32 + j];
}

// ---------------- compose: M1 = W2 @ Wih^T, M2 = rW2 @ Wih^T, v = b @ Wih^T ----------------
__global__ void compose_kernel(const float* __restrict__ W2, const float* __restrict__ rW2,
                               const float* __restrict__ Wih,
                               const float* __restrict__ b2, const float* __restrict__ rb2,
                               float* __restrict__ M1, float* __restrict__ M2,
                               float* __restrict__ v12) {
    int l = blockIdx.x / 97, j = blockIdx.x % 97;
    int k = threadIdx.x;  // 96
    const float* wih = Wih + l * 9216 + k * 96;
    if (j < 96) {
        const float* w2  = W2 + l * 9216 + j * 96;
        const float* rw2 = rW2 + l * 9216 + j * 96;
        float a1 = 0.f, a2 = 0.f;
        for (int m = 0; m < 96; ++m) {
            float wv = wih[m];
            a1 = fmaf(w2[m], wv, a1);
            a2 = fmaf(rw2[m], wv, a2);
        }
        M1[l * 9216 + j * 96 + k] = a1;
        M2[l * 9216 + j * 96 + k] = a2;
    } else {
        const float* bb = b2 + l * 96;
        const float* rbb = rb2 + l * 96;
        float a1 = 0.f, a2 = 0.f;
        for (int m = 0; m < 96; ++m) {
            float wv = wih[m];
            a1 = fmaf(bb[m], wv, a1);
            a2 = fmaf(rbb[m], wv, a2);
        }
        v12[l * 192 + k] = a1;
        v12[l * 192 + 96 + k] = a2;
    }
}

// ---------------- repack weights to col-major packed bf16 MFMA B-fragments ----------------
// M1bc/M2bc: [l][96 cols][48 words]; Whhbc: [l][96 cols][16 words]; W1bc: [l][384 cols][16 words]
// W1bc col ranges: 0..95 PaF(src-half msg), 96..191 PbF(dst-half msg), 192..287 PaR, 288..383 PbR
__global__ void repack_kernel(const float* __restrict__ M1, const float* __restrict__ M2,
                              const float* __restrict__ WhhT,
                              const float* __restrict__ W1f, const float* __restrict__ W1r,
                              unsigned* __restrict__ M1bc, unsigned* __restrict__ M2bc,
                              unsigned* __restrict__ Whhbc, unsigned* __restrict__ W1bc) {
    int idx = blockIdx.x * 256 + threadIdx.x;
    if (idx < 13824) {
        int l = idx / 4608, r = idx % 4608, c = r / 48, wd = r % 48;
        const float* src = M1 + l * 9216;
        M1bc[idx] = pack2bf(src[(2 * wd) * 96 + c], src[(2 * wd + 1) * 96 + c]);
    } else if (idx < 27648) {
        int j = idx - 13824;
        int l = j / 4608, r = j % 4608, c = r / 48, wd = r % 48;
        const float* src = M2 + l * 9216;
        M2bc[j] = pack2bf(src[(2 * wd) * 96 + c], src[(2 * wd + 1) * 96 + c]);
    } else if (idx < 32256) {
        int j = idx - 27648;
        int l = j / 1536, r = j % 1536, c = r / 16, wd = r % 16;
        const float* src = WhhT + l * 3072;
        Whhbc[j] = pack2bf(src[(2 * wd) * 96 + c], src[(2 * wd + 1) * 96 + c]);
    } else if (idx < 32256 + 18432) {
        int j = idx - 32256;
        int l = j / 6144, r = j % 6144, C = r / 16, wd = r % 16;
        const float* src; int col, rb;
        if (C < 96)       { src = W1f + l * 6144; col = C;       rb = 0;  }
        else if (C < 192) { src = W1f + l * 6144; col = C - 96;  rb = 32; }
        else if (C < 288) { src = W1r + l * 6144; col = C - 192; rb = 0;  }
        else              { src = W1r + l * 6144; col = C - 288; rb = 32; }
        W1bc[j] = pack2bf(src[(rb + 2 * wd) * 96 + col], src[(rb + 2 * wd + 1) * 96 + col]);
    }
}

// ---------------- encoder: h = IN@W + b; writes fp32 h and bf16 mirror ----------------
__global__ void __launch_bounds__(256) enc_gemm(const float* __restrict__ IN,
                                                const float* __restrict__ W, const float* __restrict__ bias,
                                                float* __restrict__ OUT, unsigned short* __restrict__ hb16, int N) {
    __shared__ float tile[64][33];
    int n0 = blockIdx.x * 64, tid = threadIdx.x;
    for (int idx = tid; idx < 64 * 32; idx += 256) {
        int r = idx >> 5, c = idx & 31;
        int n = n0 + r;
        tile[r][c] = (n < N) ? IN[(long)n * 32 + c] : 0.f;
    }
    __syncthreads();
    int lane = tid & 63;
    int w = __builtin_amdgcn_readfirstlane(tid >> 6);
    float acc[8] = {0};
    const float* Wp = W + w * 8;
#pragma unroll 4
    for (int j = 0; j < 32; ++j) {
        float a = tile[lane][j];
#pragma unroll
        for (int c = 0; c < 8; ++c) acc[c] = fmaf(a, Wp[j * 32 + c], acc[c]);
    }
    int n = n0 + lane;
    if (n >= N) return;
    float* outp = OUT + (long)n * 32 + w * 8;
    unsigned short* bp = hb16 + (long)n * 32 + w * 8;
#pragma unroll
    for (int c = 0; c < 8; ++c) {
        float v = acc[c] + bias[w * 8 + c];
        outp[c] = v;
        bp[c] = f2bf(v);
    }
}

// ---------------- proj via MFMA: [PaF|PbF|PaR|PbR](64 nodes x 384 cols) = hb @ W1bc, K=32 -------
// Wave w: node-tile nt=w>>1, col-group cg=w&1 (cols cg*192 + ct*16 + l15, ct=0..11).
// ct<6 -> Pa (ushort store, no bias); ct>=6 -> Pb (fp32 + b1).
__global__ void __launch_bounds__(512) proj_mfma(
    const unsigned* __restrict__ hb, const unsigned* __restrict__ W1bc,
    const float* __restrict__ b1f, const float* __restrict__ b1r,
    unsigned short* __restrict__ PaF16, float* __restrict__ PbF,
    unsigned short* __restrict__ PaR16, float* __restrict__ PbR, int N)
{
    int tid = threadIdx.x;
    int lane = tid & 63;
    int w = __builtin_amdgcn_readfirstlane(tid >> 6);   // 0..7
    int nt = w >> 1, cg = w & 1;
    int kgrp = lane >> 4, l15 = lane & 15;
    int ntile = blockIdx.x * 64 + nt * 16;
    int arow = ntile + l15;
    long arc = (arow < N) ? arow : (N - 1);
    short8 a = *(const short8*)(hb + arc * 16 + kgrp * 4);

    unsigned short* Pa16 = cg ? PaR16 : PaF16;
    float* Pb = cg ? PbR : PbF;
    const float* b1 = cg ? b1r : b1f;

    f32x4 acc[12];
#pragma unroll
    for (int ct = 0; ct < 12; ++ct) {
        int col = cg * 192 + ct * 16 + l15;
        short8 b = *(const short8*)(W1bc + (long)col * 16 + kgrp * 4);
        acc[ct] = __builtin_amdgcn_mfma_f32_16x16x32_bf16(a, b, (f32x4){0.f,0.f,0.f,0.f}, 0, 0, 0);
    }
    int nbase = ntile + kgrp * 4;
#pragma unroll
    for (int ct = 0; ct < 6; ++ct) {            // Pa cols
        int col = ct * 16 + l15;
#pragma unroll
        for (int i = 0; i < 4; ++i) {
            int n = nbase + i;
            if (n < N) Pa16[(long)n * 96 + col] = f2bf(acc[ct][i]);
        }
    }
#pragma unroll
    for (int ct = 6; ct < 12; ++ct) {           // Pb cols (+bias)
        int col = (ct - 6) * 16 + l15;
        float bv = b1[col];
#pragma unroll
        for (int i = 0; i < 4; ++i) {
            int n = nbase + i;
            if (n < N) Pb[(long)n * 96 + col] = acc[ct][i] + bv;
        }
    }
}

// ---------------- edge aggregation: gather bf16 Pa; OUTPUT packed bf16 (AFb/ARb) ----------------
__global__ void __launch_bounds__(256) agg_bf16(
    const int* __restrict__ offF, const int* __restrict__ listF,
    const int* __restrict__ offR, const int* __restrict__ listR,
    const unsigned* __restrict__ PaF, const unsigned* __restrict__ PaR,
    const float* __restrict__ PbF, const float* __restrict__ PbR,
    unsigned* __restrict__ AFb, unsigned* __restrict__ ARb, int N)
{
    const int* off; const int* list; const unsigned* Pa; const float* Pb; unsigned* AB;
    if (blockIdx.y == 0) { off = offF; list = listF; Pa = PaF; Pb = PbF; AB = AFb; }
    else                 { off = offR; list = listR; Pa = PaR; Pb = PbR; AB = ARb; }
    int n = __builtin_amdgcn_readfirstlane((blockIdx.x * 256 + threadIdx.x) >> 6);
    int lane = threadIdx.x & 63;
    if (n >= N) return;
    int li = (lane < 48) ? lane : 47;
    bool act = lane < 48;
    float sx = 0.f, sy = 0.f;
    if (act) { float2 s = *(const float2*)(Pb + (long)n * 96 + 2 * li); sx = s.x; sy = s.y; }
    float a0 = 0.f, a1 = 0.f;
    int beg = off[n], end = off[n + 1];
    int i = beg;
    for (; i + 8 <= end; i += 8) {              // 8 gathers in flight
        unsigned u[8];
#pragma unroll
        for (int q = 0; q < 8; ++q) u[q] = Pa[(long)list[i + q] * 48 + li];
#pragma unroll
        for (int q = 0; q < 8; ++q) {
            a0 += fmaxf(__uint_as_float(u[q] << 16) + sx, 0.f);
            a1 += fmaxf(__uint_as_float(u[q] & 0xffff0000u) + sy, 0.f);
        }
    }
    for (; i < end; ++i) {
        unsigned u = Pa[(long)list[i] * 48 + li];
        a0 += fmaxf(__uint_as_float(u << 16) + sx, 0.f);
        a1 += fmaxf(__uint_as_float(u & 0xffff0000u) + sy, 0.f);
    }
    if (act) AB[(long)n * 48 + li] = pack2bf(a0, a1);
}

// ---------------- gru3: MFMA gates; writes fp32 h' and bf16 mirror ----------------
__global__ void __launch_bounds__(512) gru3_kernel(
    const unsigned* __restrict__ AFb, const unsigned* __restrict__ ARb,
    const unsigned* __restrict__ M1bc, const unsigned* __restrict__ M2bc,
    const unsigned* __restrict__ Whhbc,
    const float* __restrict__ v12,
    const int* __restrict__ offF, const int* __restrict__ offR,
    const float* __restrict__ h, const unsigned* __restrict__ hb,
    const float* __restrict__ bih, const float* __restrict__ bhh,
    float* __restrict__ hout, unsigned short* __restrict__ hbout, int N)
{
    int tid = threadIdx.x;
    int lane = tid & 63;
    int w = __builtin_amdgcn_readfirstlane(tid >> 6);   // 0..7
    int nt = w >> 1, cg = w & 1;
    int kgrp = lane >> 4;
    int c = cg * 16 + (lane & 15);
    int ntile = blockIdx.x * 64 + nt * 16;
    int arow = ntile + (lane & 15);
    long arc = (arow < N) ? arow : (N - 1);

    f32x4 acc[3]; f32x4 gh[3];
#pragma unroll
    for (int g = 0; g < 3; ++g) { acc[g] = (f32x4){0.f,0.f,0.f,0.f}; gh[g] = (f32x4){0.f,0.f,0.f,0.f}; }

    const unsigned* afp = AFb + arc * 48 + kgrp * 4;
    const unsigned* arp = ARb + arc * 48 + kgrp * 4;
#pragma unroll
    for (int k0 = 0; k0 < 3; ++k0) {
        short8 a = *(const short8*)(afp + k0 * 16);
#pragma unroll
        for (int g = 0; g < 3; ++g) {
            int col = g * 32 + c;
            short8 b = *(const short8*)(M1bc + (long)col * 48 + k0 * 16 + kgrp * 4);
            acc[g] = __builtin_amdgcn_mfma_f32_16x16x32_bf16(a, b, acc[g], 0, 0, 0);
        }
    }
#pragma unroll
    for (int k0 = 0; k0 < 3; ++k0) {
        short8 a = *(const short8*)(arp + k0 * 16);
#pragma unroll
        for (int g = 0; g < 3; ++g) {
            int col = g * 32 + c;
            short8 b = *(const short8*)(M2bc + (long)col * 48 + k0 * 16 + kgrp * 4);
            acc[g] = __builtin_amdgcn_mfma_f32_16x16x32_bf16(a, b, acc[g], 0, 0, 0);
        }
    }
    {
        short8 ha = *(const short8*)(hb + arc * 16 + kgrp * 4);
#pragma unroll
        for (int g = 0; g < 3; ++g) {
            int col = g * 32 + c;
            short8 b = *(const short8*)(Whhbc + (long)col * 16 + kgrp * 4);
            gh[g] = __builtin_amdgcn_mfma_f32_16x16x32_bf16(ha, b, gh[g], 0, 0, 0);
        }
    }

    float v1r[3], v2r[3], bihv[3], bhhv[3];
#pragma unroll
    for (int g = 0; g < 3; ++g) {
        int col = g * 32 + c;
        v1r[g] = v12[col]; v2r[g] = v12[96 + col];
        bihv[g] = bih[col]; bhhv[g] = bhh[col];
    }
    int nbase = ntile + kgrp * 4;
#pragma unroll
    for (int i = 0; i < 4; ++i) {
        int n = nbase + i;
        if (n < N) {
            float dF = (float)(offF[n + 1] - offF[n]);
            float dR = (float)(offR[n + 1] - offR[n]);
            float gir = acc[0][i] + dF * v1r[0] + dR * v2r[0] + bihv[0];
            float giz = acc[1][i] + dF * v1r[1] + dR * v2r[1] + bihv[1];
            float gin = acc[2][i] + dF * v1r[2] + dR * v2r[2] + bihv[2];
            float r = 1.f / (1.f + __expf(-(gir + gh[0][i] + bhhv[0])));
            float z = 1.f / (1.f + __expf(-(giz + gh[1][i] + bhhv[1])));
            float nn = tanhf(gin + r * (gh[2][i] + bhhv[2]));
            float hv = h[(long)n * 32 + c];
            float vout = (1.f - z) * nn + z * hv;
            hout[(long)n * 32 + c] = vout;
            hbout[(long)n * 32 + c] = f2bf(vout);
        }
    }
}

// ---------------- graph aggregator ----------------
__global__ void __launch_bounds__(128) graph_agg(const float* __restrict__ h, const float* __restrict__ W1,
                          const float* __restrict__ b1, const int* __restrict__ gidx,
                          float* __restrict__ gs, int N, int chunk) {
    int k = threadIdx.x;  // 128
    int n_start = blockIdx.x * chunk;
    if (n_start >= N) return;
    int n_end = min(n_start + chunk, N);
    float w1[32], w2[32];
#pragma unroll
    for (int j = 0; j < 32; ++j) {
        w1[j] = W1[j * 256 + k];
        w2[j] = W1[j * 256 + 128 + k];
    }
    float bb1 = b1[k], bb2 = b1[128 + k];
    float acc = 0.f;
    int cur = gidx[n_start];
    for (int n = n_start; n < n_end; ++n) {
        int g = gidx[n];
        if (g != cur) { atomicAdd(&gs[cur * 128 + k], acc); acc = 0.f; cur = g; }
        float g1 = bb1, g2 = bb2;
#pragma unroll
        for (int j = 0; j < 32; ++j) {
            float hv = h[(long)n * 32 + j];
            g1 = fmaf(hv, w1[j], g1);
            g2 = fmaf(hv, w2[j], g2);
        }
        acc += (1.f / (1.f + __expf(-g1))) * g2;
    }
    atomicAdd(&gs[cur * 128 + k], acc);
}

__global__ void final_gemm(const float* __restrict__ gs, const float* __restrict__ W,
                           const float* __restrict__ b, float* __restrict__ out) {
    int g = blockIdx.x, k = threadIdx.x;
    float a = b[k];
#pragma unroll 8
    for (int j = 0; j < 128; ++j) a = fmaf(gs[g * 128 + j], W[j * 128 + k], a);
    out[g * 128 + k] = a;
}

extern "C" void kernel_launch(void* const* d_in, const int* in_sizes, int n_in,
                              void* d_out, int out_size, void* d_ws, size_t ws_size,
                              hipStream_t stream) {
    const float* node_features = (const float*)d_in[0];
    const float* enc_W  = (const float*)d_in[1];
    const float* enc_b  = (const float*)d_in[2];
    const float* msg_W1 = (const float*)d_in[3];
    const float* msg_b1 = (const float*)d_in[4];
    const float* msg_W2 = (const float*)d_in[5];
    const float* msg_b2 = (const float*)d_in[6];
    const float* rmsg_W1 = (const float*)d_in[7];
    const float* rmsg_b1 = (const float*)d_in[8];
    const float* rmsg_W2 = (const float*)d_in[9];
    const float* rmsg_b2 = (const float*)d_in[10];
    const float* gru_Wih = (const float*)d_in[11];
    const float* gru_Whh = (const float*)d_in[12];
    const float* gru_bih = (const float*)d_in[13];
    const float* gru_bhh = (const float*)d_in[14];
    const float* agg_W1 = (const float*)d_in[15];
    const float* agg_b1 = (const float*)d_in[16];
    const float* agg_W2 = (const float*)d_in[17];
    const float* agg_b2 = (const float*)d_in[18];
    const int* from_idx = (const int*)d_in[19];
    const int* to_idx   = (const int*)d_in[20];
    const int* graph_idx = (const int*)d_in[21];

    const int N = in_sizes[0] / 32;
    const int E = in_sizes[19];
    const int NG = out_size / 128;
    float* out = (float*)d_out;

    char* ws = (char*)d_ws;
    auto alloc = [&](size_t b) { void* p = (void*)ws; ws += (b + 255) & ~(size_t)255; return p; };
    int* cnt_to   = (int*)alloc((size_t)N * 4);
    int* cnt_from = (int*)alloc((size_t)N * 4);
    int* off_to   = (int*)alloc((size_t)(N + 1) * 4);
    int* off_from = (int*)alloc((size_t)(N + 1) * 4);
    int* list_to  = (int*)alloc((size_t)E * 4);
    int* list_from= (int*)alloc((size_t)E * 4);
    float* h0  = (float*)alloc((size_t)N * 32 * 4);
    float* h1  = (float*)alloc((size_t)N * 32 * 4);
    unsigned* PaF = (unsigned*)alloc((size_t)N * 48 * 4);
    unsigned* PaR = (unsigned*)alloc((size_t)N * 48 * 4);
    float* PbF = (float*)alloc((size_t)N * 96 * 4);
    float* PbR = (float*)alloc((size_t)N * 96 * 4);
    unsigned* AFb = (unsigned*)alloc((size_t)N * 48 * 4);
    unsigned* ARb = (unsigned*)alloc((size_t)N * 48 * 4);
    unsigned* hb0 = (unsigned*)alloc((size_t)N * 16 * 4);
    unsigned* hb1 = (unsigned*)alloc((size_t)N * 16 * 4);
    float* WhhT = (float*)alloc((size_t)3 * 32 * 96 * 4);
    float* M1   = (float*)alloc((size_t)3 * 96 * 96 * 4);
    float* M2   = (float*)alloc((size_t)3 * 96 * 96 * 4);
    float* v12  = (float*)alloc((size_t)3 * 192 * 4);
    unsigned* M1bc = (unsigned*)alloc((size_t)13824 * 4);
    unsigned* M2bc = (unsigned*)alloc((size_t)13824 * 4);
    unsigned* Whhbc = (unsigned*)alloc((size_t)4608 * 4);
    unsigned* W1bc  = (unsigned*)alloc((size_t)18432 * 4);
    float* gs   = (float*)alloc((size_t)NG * 128 * 4);
    const int nblk = (N + SB - 1) / SB;
    int* bsum  = (int*)alloc((size_t)2 * nblk * 4);
    int* bbase = (int*)alloc((size_t)2 * nblk * 4);
    // rank arrays alias Pb buffers (dead before proj writes them)
    int* rank_to   = (int*)PbF;
    int* rank_from = (int*)PbR;

    hipMemsetAsync(cnt_to, 0, (size_t)N * 4, stream);
    hipMemsetAsync(cnt_from, 0, (size_t)N * 4, stream);
    hipMemsetAsync(gs, 0, (size_t)NG * 128 * 4, stream);

    int gE = (E + 255) / 256;
    count_rank_kernel<<<gE, 256, 0, stream>>>(from_idx, to_idx, cnt_to, cnt_from, rank_to, rank_from, E);
    dim3 gScan(nblk, 2);
    scanA_kernel<<<gScan, SB, 0, stream>>>(cnt_to, cnt_from, bsum, nblk, N);
    scanB_kernel<<<1, 64, 0, stream>>>(bsum, bbase, off_to, off_from, nblk, N);
    scanC_kernel<<<gScan, SB, 0, stream>>>(cnt_to, cnt_from, bbase, off_to, off_from, nblk, N);
    fill_kernel<<<gE, 256, 0, stream>>>(from_idx, to_idx, off_to, off_from, rank_to, rank_from,
                                        list_to, list_from, E);

    transpose_whh<<<(3 * 32 * 96 + 255) / 256, 256, 0, stream>>>(gru_Whh, WhhT);
    compose_kernel<<<3 * 97, 96, 0, stream>>>(msg_W2, rmsg_W2, gru_Wih, msg_b2, rmsg_b2, M1, M2, v12);
    repack_kernel<<<(32256 + 18432 + 255) / 256, 256, 0, stream>>>(M1, M2, WhhT, msg_W1, rmsg_W1,
                                                                   M1bc, M2bc, Whhbc, W1bc);

    int gN64 = (N + 63) / 64;
    enc_gemm<<<gN64, 256, 0, stream>>>(node_features, enc_W, enc_b, h0, (unsigned short*)hb0, N);

    float* hcur = h0; float* hnext = h1;
    unsigned* hbcur = hb0; unsigned* hbnext = hb1;
    dim3 gAgg((N + 3) / 4, 2);
    for (int l = 0; l < 3; ++l) {
        proj_mfma<<<gN64, 512, 0, stream>>>(hbcur, W1bc + l * 6144,
                                            msg_b1 + l * 96, rmsg_b1 + l * 96,
                                            (unsigned short*)PaF, PbF, (unsigned short*)PaR, PbR, N);
        agg_bf16<<<gAgg, 256, 0, stream>>>(off_to, list_to, off_from, list_from,
                                           PaF, PaR, PbF, PbR, AFb, ARb, N);
        gru3_kernel<<<gN64, 512, 0, stream>>>(AFb, ARb, M1bc + l * 4608, M2bc + l * 4608,
                                              Whhbc + l * 1536, v12 + l * 192,
                                              off_to, off_from, hcur, hbcur,
                                              gru_bih + l * 96, gru_bhh + l * 96, hnext,
                                              (unsigned short*)hbnext, N);
        float* t = hcur; hcur = hnext; hnext = t;
        unsigned* tb = hbcur; hbcur = hbnext; hbnext = tb;
    }

    const int chunk = 32;
    graph_agg<<<(N + chunk - 1) / chunk, 128, 0, stream>>>(hcur, agg_W1, agg_b1, graph_idx, gs, N, chunk);
    final_gemm<<<NG, 128, 0, stream>>>(gs, agg_W2, agg_b2, out);
}